// Round 1
// baseline (1867.252 us; speedup 1.0000x reference)
//
#include <hip/hip_runtime.h>
#include <math.h>

#define N_NODES 100000
#define N_EDGES 3200000

// ---------------------------------------------------------------------------
// K1: edge scatter-add.  sums[src] += concat(x,pos,z)[dst]
// one thread per (edge, feature); 2 edges per 256-thread block
// ---------------------------------------------------------------------------
__global__ __launch_bounds__(256) void scatter_kernel(
    const int* __restrict__ ei,      // [2, E] int32
    const float* __restrict__ x,     // [N, 124]
    const float* __restrict__ pos,   // [N, 3]
    const float* __restrict__ z,     // [N]
    float* __restrict__ sums)        // [N, 128]
{
    long long idx = (long long)blockIdx.x * blockDim.x + threadIdx.x;
    int e = (int)(idx >> 7);
    int f = (int)(idx & 127);
    if (e >= N_EDGES) return;
    int src = ei[e];
    int dst = ei[N_EDGES + e];
    float v;
    if (f < 124)      v = x[dst * 124 + f];
    else if (f < 127) v = pos[dst * 3 + (f - 124)];
    else              v = z[dst];
    atomicAdd(&sums[src * 128 + f], v);
}

// ---------------------------------------------------------------------------
// K2: per-row L2 normalize, in place.  One wave (64 lanes) per node.
// ---------------------------------------------------------------------------
__global__ __launch_bounds__(256) void normalize_kernel(float* __restrict__ sums)
{
    int wid  = (blockIdx.x * blockDim.x + threadIdx.x) >> 6;  // node
    int lane = threadIdx.x & 63;
    if (wid >= N_NODES) return;
    float a = sums[wid * 128 + lane];
    float b = sums[wid * 128 + 64 + lane];
    float ss = a * a + b * b;
    #pragma unroll
    for (int off = 32; off > 0; off >>= 1) ss += __shfl_xor(ss, off, 64);
    float inv = 1.0f / sqrtf(ss);
    sums[wid * 128 + lane]      = a * inv;
    sums[wid * 128 + 64 + lane] = b * inv;
}

// ---------------------------------------------------------------------------
// K3: f32 tiled GEMM  C[M,256] = act(A[M,K] @ B[K,256] + bias)
// BM=64, BN=64, BK=16; 256 threads; 4x4 microtile per thread
// ---------------------------------------------------------------------------
__global__ __launch_bounds__(256) void gemm_relu_kernel(
    const float* __restrict__ A, const float* __restrict__ B,
    const float* __restrict__ bias, float* __restrict__ C,
    int M, int K, int doRelu)
{
    const int NCOL = 256;
    __shared__ float As[16][65];
    __shared__ float Bs[16][64];

    int row0 = blockIdx.x * 64;
    int col0 = blockIdx.y * 64;
    int tid = threadIdx.x;
    int ty = tid >> 4, tx = tid & 15;

    float acc[4][4] = {{0.f}};

    for (int k0 = 0; k0 < K; k0 += 16) {
        // A tile 64x16 -> As transposed
        {
            int m  = tid >> 2;
            int kk = (tid & 3) * 4;
            int row = row0 + m;
            float4 v = make_float4(0.f, 0.f, 0.f, 0.f);
            if (row < M)
                v = *reinterpret_cast<const float4*>(&A[(long long)row * K + k0 + kk]);
            As[kk + 0][m] = v.x; As[kk + 1][m] = v.y;
            As[kk + 2][m] = v.z; As[kk + 3][m] = v.w;
        }
        // B tile 16x64
        {
            int kk = tid >> 4;
            int n  = (tid & 15) * 4;
            float4 v = *reinterpret_cast<const float4*>(&B[(k0 + kk) * NCOL + col0 + n]);
            *reinterpret_cast<float4*>(&Bs[kk][n]) = v;
        }
        __syncthreads();
        #pragma unroll
        for (int kk = 0; kk < 16; ++kk) {
            float a[4], b[4];
            #pragma unroll
            for (int i = 0; i < 4; ++i) a[i] = As[kk][ty * 4 + i];
            #pragma unroll
            for (int j = 0; j < 4; ++j) b[j] = Bs[kk][tx * 4 + j];
            #pragma unroll
            for (int i = 0; i < 4; ++i)
                #pragma unroll
                for (int j = 0; j < 4; ++j)
                    acc[i][j] += a[i] * b[j];
        }
        __syncthreads();
    }

    #pragma unroll
    for (int i = 0; i < 4; ++i) {
        int row = row0 + ty * 4 + i;
        if (row >= M) continue;
        float4 v;
        float* vp = reinterpret_cast<float*>(&v);
        #pragma unroll
        for (int j = 0; j < 4; ++j) {
            float val = acc[i][j] + bias[col0 + tx * 4 + j];
            if (doRelu) val = fmaxf(val, 0.f);
            vp[j] = val;
        }
        *reinterpret_cast<float4*>(&C[(long long)row * NCOL + col0 + tx * 4]) = v;
    }
}

// ---------------------------------------------------------------------------
// K4: per-node dot with W4 [256] + b4, block partial sums (deterministic)
// ---------------------------------------------------------------------------
__global__ __launch_bounds__(256) void outdot_kernel(
    const float* __restrict__ h3,   // [N,256] (relu already applied)
    const float* __restrict__ W4,   // [256]
    const float* __restrict__ b4,   // [1]
    float* __restrict__ partials)   // [gridDim.x]
{
    __shared__ float red[4];
    int lane = threadIdx.x & 63;
    int wid  = threadIdx.x >> 6;     // 0..3
    int wavesTotal = gridDim.x * 4;
    float local = 0.f;
    float4 w = *reinterpret_cast<const float4*>(&W4[lane * 4]);
    float bb = b4[0];
    for (int n = blockIdx.x * 4 + wid; n < N_NODES; n += wavesTotal) {
        float4 h = *reinterpret_cast<const float4*>(&h3[(long long)n * 256 + lane * 4]);
        float d = h.x * w.x + h.y * w.y + h.z * w.z + h.w * w.w;
        #pragma unroll
        for (int off = 32; off > 0; off >>= 1) d += __shfl_xor(d, off, 64);
        if (lane == 0) local += d + bb;
    }
    if (lane == 0) red[wid] = local;
    __syncthreads();
    if (threadIdx.x == 0)
        partials[blockIdx.x] = red[0] + red[1] + red[2] + red[3];
}

__global__ __launch_bounds__(256) void final_kernel(
    const float* __restrict__ partials, int n, float* __restrict__ out)
{
    __shared__ float buf[256];
    float s = 0.f;
    for (int i = threadIdx.x; i < n; i += 256) s += partials[i];
    buf[threadIdx.x] = s;
    __syncthreads();
    for (int off = 128; off > 0; off >>= 1) {
        if (threadIdx.x < off) buf[threadIdx.x] += buf[threadIdx.x + off];
        __syncthreads();
    }
    if (threadIdx.x == 0) out[0] = buf[0] / (float)N_NODES;
}

// ---------------------------------------------------------------------------
extern "C" void kernel_launch(void* const* d_in, const int* in_sizes, int n_in,
                              void* d_out, int out_size, void* d_ws, size_t ws_size,
                              hipStream_t stream)
{
    const float* x   = (const float*)d_in[0];
    const float* pos = (const float*)d_in[1];
    const float* z   = (const float*)d_in[2];
    const int*   ei  = (const int*)d_in[3];
    const float* W1  = (const float*)d_in[4];
    const float* b1  = (const float*)d_in[5];
    const float* W2  = (const float*)d_in[6];
    const float* b2  = (const float*)d_in[7];
    const float* W3  = (const float*)d_in[8];
    const float* b3  = (const float*)d_in[9];
    const float* W4  = (const float*)d_in[10];
    const float* b4  = (const float*)d_in[11];
    float* out = (float*)d_out;

    char* ws = (char*)d_ws;
    float* sums     = (float*)(ws);                            // N*128 f32 = 51.2 MB
    float* h1       = (float*)(ws + 51200000);                 // N*256 f32 = 102.4 MB
    float* h2       = (float*)(ws + 51200000 + 102400000);     // N*256 f32 = 102.4 MB
    float* partials = (float*)(ws + 51200000 + 2 * 102400000); // 1024 f32

    // zero the accumulator
    hipMemsetAsync(sums, 0, (size_t)N_NODES * 128 * sizeof(float), stream);

    // K1 scatter: E*128 threads
    {
        long long total = (long long)N_EDGES * 128;
        int blocks = (int)((total + 255) / 256);
        scatter_kernel<<<blocks, 256, 0, stream>>>(ei, x, pos, z, sums);
    }

    // K2 normalize (in place -> h0)
    normalize_kernel<<<(N_NODES + 3) / 4, 256, 0, stream>>>(sums);

    // K3..K5 GEMMs
    dim3 g1((N_NODES + 63) / 64, 4);
    gemm_relu_kernel<<<g1, 256, 0, stream>>>(sums, W1, b1, h1, N_NODES, 128, 1);
    gemm_relu_kernel<<<g1, 256, 0, stream>>>(h1,   W2, b2, h2, N_NODES, 256, 1);
    gemm_relu_kernel<<<g1, 256, 0, stream>>>(h2,   W3, b3, h1, N_NODES, 256, 1); // h3 -> h1 buffer

    // K6 out dot + partial reduce
    outdot_kernel<<<1024, 256, 0, stream>>>(h1, W4, b4, partials);

    // K7 final mean
    final_kernel<<<1, 256, 0, stream>>>(partials, 1024, out);
}

// Round 2
// 1228.875 us; speedup vs baseline: 1.5195x; 1.5195x over previous
//
#include <hip/hip_runtime.h>
#include <math.h>

#define N_NODES 100000
#define N_EDGES 3200000

// ---------------------------------------------------------------------------
// K0: pack feats[N,128] = concat(x[124], pos[3], z[1])
// ---------------------------------------------------------------------------
__global__ __launch_bounds__(256) void pack_kernel(
    const float* __restrict__ x, const float* __restrict__ pos,
    const float* __restrict__ z, float* __restrict__ feats)
{
    int idx = blockIdx.x * blockDim.x + threadIdx.x;   // N*128
    if (idx >= N_NODES * 128) return;
    int n = idx >> 7, f = idx & 127;
    float v;
    if (f < 124)      v = x[n * 124 + f];
    else if (f < 127) v = pos[n * 3 + (f - 124)];
    else              v = z[n];
    feats[idx] = v;
}

// ---------------------------------------------------------------------------
// K1: histogram of src
// ---------------------------------------------------------------------------
__global__ __launch_bounds__(256) void hist_kernel(
    const int* __restrict__ ei, int* __restrict__ counts)
{
    int e = blockIdx.x * blockDim.x + threadIdx.x;
    if (e < N_EDGES) atomicAdd(&counts[ei[e]], 1);
}

// ---------------------------------------------------------------------------
// K2: single-block exclusive scan of counts[N] -> rowptr[N+1], cursor[N]
// 1024 threads, each owns a 98-element chunk
// ---------------------------------------------------------------------------
__global__ __launch_bounds__(1024) void scan_kernel(
    const int* __restrict__ counts, int* __restrict__ rowptr,
    int* __restrict__ cursor)
{
    __shared__ int tsum[1024];
    const int CHUNK = (N_NODES + 1023) / 1024;
    int t = threadIdx.x;
    int begin = t * CHUNK;
    int end = begin + CHUNK; if (end > N_NODES) end = N_NODES;
    if (begin > N_NODES) begin = N_NODES;
    int s = 0;
    for (int i = begin; i < end; ++i) s += counts[i];
    tsum[t] = s;
    __syncthreads();
    // Hillis-Steele inclusive scan over thread sums
    for (int off = 1; off < 1024; off <<= 1) {
        int other = (t >= off) ? tsum[t - off] : 0;
        __syncthreads();
        tsum[t] += other;
        __syncthreads();
    }
    int excl = tsum[t] - s;        // exclusive offset for this thread's chunk
    int running = excl;
    for (int i = begin; i < end; ++i) {
        int c = counts[i];
        rowptr[i] = running;
        cursor[i] = running;
        running += c;
    }
    if (t == 1023) rowptr[N_NODES] = tsum[1023];
}

// ---------------------------------------------------------------------------
// K3: permute edges into CSR order: sorted_dst[bucket(src)] = dst
// ---------------------------------------------------------------------------
__global__ __launch_bounds__(256) void sortedges_kernel(
    const int* __restrict__ ei, int* __restrict__ cursor,
    int* __restrict__ sorted_dst)
{
    int e = blockIdx.x * blockDim.x + threadIdx.x;
    if (e >= N_EDGES) return;
    int src = ei[e];
    int dst = ei[N_EDGES + e];
    int p = atomicAdd(&cursor[src], 1);
    sorted_dst[p] = dst;
}

// ---------------------------------------------------------------------------
// K4: aggregate + fused L2 normalize. One wave per node; lane owns
// features {2*lane, 2*lane+1} as a float2.
// ---------------------------------------------------------------------------
__global__ __launch_bounds__(256) void aggregate_kernel(
    const int* __restrict__ rowptr, const int* __restrict__ sorted_dst,
    const float2* __restrict__ feats2, float* __restrict__ h0)
{
    int node = (blockIdx.x * blockDim.x + threadIdx.x) >> 6;
    int lane = threadIdx.x & 63;
    if (node >= N_NODES) return;
    int start = rowptr[node], end = rowptr[node + 1];
    float ax = 0.f, ay = 0.f;
    int i = start;
    int dst_next = (i < end) ? sorted_dst[i] : 0;
    while (i < end) {
        int dst = dst_next;
        ++i;
        if (i < end) dst_next = sorted_dst[i];
        float2 v = feats2[(long long)dst * 64 + lane];
        ax += v.x; ay += v.y;
    }
    float ss = ax * ax + ay * ay;
    #pragma unroll
    for (int off = 32; off > 0; off >>= 1) ss += __shfl_xor(ss, off, 64);
    float inv = 1.0f / sqrtf(ss);
    float2 o; o.x = ax * inv; o.y = ay * inv;
    *reinterpret_cast<float2*>(&h0[(long long)node * 128 + lane * 2]) = o;
}

// ---------------------------------------------------------------------------
// K5: f32 tiled GEMM  C[M,256] = relu(A[M,K] @ B[K,256] + bias)
// ---------------------------------------------------------------------------
__global__ __launch_bounds__(256) void gemm_relu_kernel(
    const float* __restrict__ A, const float* __restrict__ B,
    const float* __restrict__ bias, float* __restrict__ C,
    int M, int K, int doRelu)
{
    const int NCOL = 256;
    __shared__ float As[16][65];
    __shared__ float Bs[16][64];

    int row0 = blockIdx.x * 64;
    int col0 = blockIdx.y * 64;
    int tid = threadIdx.x;
    int ty = tid >> 4, tx = tid & 15;

    float acc[4][4] = {{0.f}};

    for (int k0 = 0; k0 < K; k0 += 16) {
        {
            int m  = tid >> 2;
            int kk = (tid & 3) * 4;
            int row = row0 + m;
            float4 v = make_float4(0.f, 0.f, 0.f, 0.f);
            if (row < M)
                v = *reinterpret_cast<const float4*>(&A[(long long)row * K + k0 + kk]);
            As[kk + 0][m] = v.x; As[kk + 1][m] = v.y;
            As[kk + 2][m] = v.z; As[kk + 3][m] = v.w;
        }
        {
            int kk = tid >> 4;
            int n  = (tid & 15) * 4;
            float4 v = *reinterpret_cast<const float4*>(&B[(k0 + kk) * NCOL + col0 + n]);
            *reinterpret_cast<float4*>(&Bs[kk][n]) = v;
        }
        __syncthreads();
        #pragma unroll
        for (int kk = 0; kk < 16; ++kk) {
            float a[4], b[4];
            #pragma unroll
            for (int i = 0; i < 4; ++i) a[i] = As[kk][ty * 4 + i];
            #pragma unroll
            for (int j = 0; j < 4; ++j) b[j] = Bs[kk][tx * 4 + j];
            #pragma unroll
            for (int i = 0; i < 4; ++i)
                #pragma unroll
                for (int j = 0; j < 4; ++j)
                    acc[i][j] += a[i] * b[j];
        }
        __syncthreads();
    }

    #pragma unroll
    for (int i = 0; i < 4; ++i) {
        int row = row0 + ty * 4 + i;
        if (row >= M) continue;
        float4 v;
        float* vp = reinterpret_cast<float*>(&v);
        #pragma unroll
        for (int j = 0; j < 4; ++j) {
            float val = acc[i][j] + bias[col0 + tx * 4 + j];
            if (doRelu) val = fmaxf(val, 0.f);
            vp[j] = val;
        }
        *reinterpret_cast<float4*>(&C[(long long)row * NCOL + col0 + tx * 4]) = v;
    }
}

// ---------------------------------------------------------------------------
// K6: per-node dot with W4 [256] + b4 -> block partial sums
// ---------------------------------------------------------------------------
__global__ __launch_bounds__(256) void outdot_kernel(
    const float* __restrict__ h3, const float* __restrict__ W4,
    const float* __restrict__ b4, float* __restrict__ partials)
{
    __shared__ float red[4];
    int lane = threadIdx.x & 63;
    int wid  = threadIdx.x >> 6;
    int wavesTotal = gridDim.x * 4;
    float local = 0.f;
    float4 w = *reinterpret_cast<const float4*>(&W4[lane * 4]);
    float bb = b4[0];
    for (int n = blockIdx.x * 4 + wid; n < N_NODES; n += wavesTotal) {
        float4 h = *reinterpret_cast<const float4*>(&h3[(long long)n * 256 + lane * 4]);
        float d = h.x * w.x + h.y * w.y + h.z * w.z + h.w * w.w;
        #pragma unroll
        for (int off = 32; off > 0; off >>= 1) d += __shfl_xor(d, off, 64);
        if (lane == 0) local += d + bb;
    }
    if (lane == 0) red[wid] = local;
    __syncthreads();
    if (threadIdx.x == 0)
        partials[blockIdx.x] = red[0] + red[1] + red[2] + red[3];
}

__global__ __launch_bounds__(256) void final_kernel(
    const float* __restrict__ partials, int n, float* __restrict__ out)
{
    __shared__ float buf[256];
    float s = 0.f;
    for (int i = threadIdx.x; i < n; i += 256) s += partials[i];
    buf[threadIdx.x] = s;
    __syncthreads();
    for (int off = 128; off > 0; off >>= 1) {
        if (threadIdx.x < off) buf[threadIdx.x] += buf[threadIdx.x + off];
        __syncthreads();
    }
    if (threadIdx.x == 0) out[0] = buf[0] / (float)N_NODES;
}

// ---------------------------------------------------------------------------
extern "C" void kernel_launch(void* const* d_in, const int* in_sizes, int n_in,
                              void* d_out, int out_size, void* d_ws, size_t ws_size,
                              hipStream_t stream)
{
    const float* x   = (const float*)d_in[0];
    const float* pos = (const float*)d_in[1];
    const float* z   = (const float*)d_in[2];
    const int*   ei  = (const int*)d_in[3];
    const float* W1  = (const float*)d_in[4];
    const float* b1  = (const float*)d_in[5];
    const float* W2  = (const float*)d_in[6];
    const float* b2  = (const float*)d_in[7];
    const float* W3  = (const float*)d_in[8];
    const float* b3  = (const float*)d_in[9];
    const float* W4  = (const float*)d_in[10];
    const float* b4  = (const float*)d_in[11];
    float* out = (float*)d_out;

    char* ws = (char*)d_ws;
    // layout (bytes):
    //   h0      @ 0           51,200,000   normalized features [N,128]
    //   feats   @ 51,200,000  51,200,000   packed input feats (dies when GEMM1 writes h1)
    //   h1      @ 51,200,000  102,400,000  (GEMM1 out, GEMM3 out)
    //   h2      @ 153,600,000 102,400,000  (GEMM2 out; sort scratch lives here first)
    //     counts     @ 153,600,000   400,000
    //     rowptr     @ 154,000,000   400,004
    //     cursor     @ 154,400,008   400,000
    //     sorted_dst @ 154,800,008   12,800,000
    //   partials @ 256,000,000  4,096
    float* h0        = (float*)(ws);
    float* feats     = (float*)(ws + 51200000);
    float* h1        = (float*)(ws + 51200000);
    float* h2        = (float*)(ws + 153600000);
    int*   counts    = (int*)  (ws + 153600000);
    int*   rowptr    = (int*)  (ws + 154000000);
    int*   cursor    = (int*)  (ws + 154400008);
    int*   sortedDst = (int*)  (ws + 154800008);
    float* partials  = (float*)(ws + 256000000);

    // K0: pack features
    pack_kernel<<<(N_NODES * 128 + 255) / 256, 256, 0, stream>>>(x, pos, z, feats);

    // K1: histogram
    hipMemsetAsync(counts, 0, (size_t)N_NODES * sizeof(int), stream);
    hist_kernel<<<(N_EDGES + 255) / 256, 256, 0, stream>>>(ei, counts);

    // K2: scan -> rowptr, cursor
    scan_kernel<<<1, 1024, 0, stream>>>(counts, rowptr, cursor);

    // K3: CSR permute
    sortedges_kernel<<<(N_EDGES + 255) / 256, 256, 0, stream>>>(ei, cursor, sortedDst);

    // K4: aggregate + normalize -> h0
    aggregate_kernel<<<(N_NODES * 64 + 255) / 256, 256, 0, stream>>>(
        rowptr, sortedDst, (const float2*)feats, h0);

    // K5..K7: GEMMs
    dim3 g1((N_NODES + 63) / 64, 4);
    gemm_relu_kernel<<<g1, 256, 0, stream>>>(h0, W1, b1, h1, N_NODES, 128, 1);
    gemm_relu_kernel<<<g1, 256, 0, stream>>>(h1, W2, b2, h2, N_NODES, 256, 1);
    gemm_relu_kernel<<<g1, 256, 0, stream>>>(h2, W3, b3, h1, N_NODES, 256, 1);

    // K8: out dot + partial reduce
    outdot_kernel<<<1024, 256, 0, stream>>>(h1, W4, b4, partials);

    // K9: final mean
    final_kernel<<<1, 256, 0, stream>>>(partials, 1024, out);
}

// Round 3
// 889.877 us; speedup vs baseline: 2.0983x; 1.3809x over previous
//
#include <hip/hip_runtime.h>
#include <math.h>

#define N_NODES 100000
#define N_EDGES 3200000
#define SCAN_BLOCKS ((N_NODES + 255) / 256)   // 391

typedef _Float16 half8 __attribute__((ext_vector_type(8)));
typedef float f32x4 __attribute__((ext_vector_type(4)));

__device__ __forceinline__ void gload16(const void* gsrc, void* ldst) {
    __builtin_amdgcn_global_load_lds(
        (const __attribute__((address_space(1))) unsigned int*)gsrc,
        (__attribute__((address_space(3))) unsigned int*)ldst,
        16, 0, 0);
}

// ---------------------------------------------------------------------------
// K0: pack feats[N,128] = concat(x[124], pos[3], z[1])  (f32)
// ---------------------------------------------------------------------------
__global__ __launch_bounds__(256) void pack_kernel(
    const float* __restrict__ x, const float* __restrict__ pos,
    const float* __restrict__ z, float* __restrict__ feats)
{
    int idx = blockIdx.x * blockDim.x + threadIdx.x;
    if (idx >= N_NODES * 128) return;
    int n = idx >> 7, f = idx & 127;
    float v;
    if (f < 124)      v = x[n * 124 + f];
    else if (f < 127) v = pos[n * 3 + (f - 124)];
    else              v = z[n];
    feats[idx] = v;
}

// ---------------------------------------------------------------------------
// weight prep: W[K,256] f32 -> WThi/WTlo [256,K] f16 (hi/lo split)
// ---------------------------------------------------------------------------
__global__ __launch_bounds__(256) void wprep_kernel(
    const float* __restrict__ W, int K,
    _Float16* __restrict__ WThi, _Float16* __restrict__ WTlo)
{
    int idx = blockIdx.x * blockDim.x + threadIdx.x;
    if (idx >= K * 256) return;
    int k = idx >> 8, c = idx & 255;
    float v = W[idx];
    _Float16 hi = (_Float16)v;
    _Float16 lo = (_Float16)(v - (float)hi);
    WThi[c * K + k] = hi;
    WTlo[c * K + k] = lo;
}

// ---------------------------------------------------------------------------
// K1: histogram of src
// ---------------------------------------------------------------------------
__global__ __launch_bounds__(256) void hist_kernel(
    const int* __restrict__ ei, int* __restrict__ counts)
{
    int e = blockIdx.x * blockDim.x + threadIdx.x;
    if (e < N_EDGES) {
        int s = __builtin_nontemporal_load(&ei[e]);
        atomicAdd(&counts[s], 1);
    }
}

// ---------------------------------------------------------------------------
// K2a/b/c: multi-block exclusive scan of counts -> rowptr, cursor
// ---------------------------------------------------------------------------
__global__ __launch_bounds__(256) void blocksum_kernel(
    const int* __restrict__ counts, int* __restrict__ bsums)
{
    __shared__ int red[4];
    int i = blockIdx.x * 256 + threadIdx.x;
    int v = (i < N_NODES) ? counts[i] : 0;
    #pragma unroll
    for (int off = 32; off > 0; off >>= 1) v += __shfl_xor(v, off, 64);
    if ((threadIdx.x & 63) == 0) red[threadIdx.x >> 6] = v;
    __syncthreads();
    if (threadIdx.x == 0) bsums[blockIdx.x] = red[0] + red[1] + red[2] + red[3];
}

__global__ __launch_bounds__(512) void scanbsums_kernel(
    int* __restrict__ bsums, int* __restrict__ rowptr)
{
    __shared__ int s[512];
    int t = threadIdx.x;
    int v = (t < SCAN_BLOCKS) ? bsums[t] : 0;
    s[t] = v;
    __syncthreads();
    for (int off = 1; off < 512; off <<= 1) {
        int o = (t >= off) ? s[t - off] : 0;
        __syncthreads();
        s[t] += o;
        __syncthreads();
    }
    if (t < SCAN_BLOCKS) bsums[t] = s[t] - v;   // exclusive block offset
    if (t == SCAN_BLOCKS - 1) rowptr[N_NODES] = s[t];
}

__global__ __launch_bounds__(256) void blockscan_kernel(
    const int* __restrict__ counts, const int* __restrict__ bsums,
    int* __restrict__ rowptr, int* __restrict__ cursor)
{
    __shared__ int s[256];
    int t = threadIdx.x;
    int i = blockIdx.x * 256 + t;
    int v = (i < N_NODES) ? counts[i] : 0;
    s[t] = v;
    __syncthreads();
    for (int off = 1; off < 256; off <<= 1) {
        int o = (t >= off) ? s[t - off] : 0;
        __syncthreads();
        s[t] += o;
        __syncthreads();
    }
    if (i < N_NODES) {
        int excl = s[t] - v + bsums[blockIdx.x];
        rowptr[i] = excl;
        cursor[i] = excl;
    }
}

// ---------------------------------------------------------------------------
// K3: permute edges into CSR order
// ---------------------------------------------------------------------------
__global__ __launch_bounds__(256) void sortedges_kernel(
    const int* __restrict__ ei, int* __restrict__ cursor,
    int* __restrict__ sorted_dst)
{
    int e = blockIdx.x * blockDim.x + threadIdx.x;
    if (e >= N_EDGES) return;
    int src = __builtin_nontemporal_load(&ei[e]);
    int dst = __builtin_nontemporal_load(&ei[N_EDGES + e]);
    int p = atomicAdd(&cursor[src], 1);
    __builtin_nontemporal_store(dst, &sorted_dst[p]);
}

// ---------------------------------------------------------------------------
// K4: aggregate + fused L2 normalize -> h0 (f16). One wave per node.
// ---------------------------------------------------------------------------
__global__ __launch_bounds__(256) void aggregate_kernel(
    const int* __restrict__ rowptr, const int* __restrict__ sorted_dst,
    const float2* __restrict__ feats2, _Float16* __restrict__ h0)
{
    int node = (blockIdx.x * blockDim.x + threadIdx.x) >> 6;
    int lane = threadIdx.x & 63;
    if (node >= N_NODES) return;
    int start = rowptr[node], end = rowptr[node + 1];
    float ax = 0.f, ay = 0.f;
    int i = start;
    int dst_next = (i < end) ? sorted_dst[i] : 0;
    while (i < end) {
        int dst = dst_next;
        ++i;
        if (i < end) dst_next = sorted_dst[i];
        float2 v = feats2[(long long)dst * 64 + lane];
        ax += v.x; ay += v.y;
    }
    float ss = ax * ax + ay * ay;
    #pragma unroll
    for (int off = 32; off > 0; off >>= 1) ss += __shfl_xor(ss, off, 64);
    float inv = 1.0f / sqrtf(ss);
    union { unsigned int u; _Float16 h[2]; } cv;
    cv.h[0] = (_Float16)(ax * inv);
    cv.h[1] = (_Float16)(ay * inv);
    *reinterpret_cast<unsigned int*>(&h0[(long long)node * 128 + lane * 2]) = cv.u;
}

// ---------------------------------------------------------------------------
// K5: MFMA GEMM  C[M,256] = relu(A[M,K] @ (WThi+WTlo)^T + bias), all f16 I/O
// BM=64, BN=256, BK=32; 256 threads = 4 waves in 2x2
// ---------------------------------------------------------------------------
__global__ __launch_bounds__(256) void gemm_f16_kernel(
    const _Float16* __restrict__ A,     // [M][K]
    const _Float16* __restrict__ BThi,  // [256][K]
    const _Float16* __restrict__ BTlo,  // [256][K]
    const float* __restrict__ bias,     // [256]
    _Float16* __restrict__ C,           // [M][256]
    int M, int K, int doRelu)
{
    __shared__ __align__(16) _Float16 sA[64 * 32];      // 4 KB
    __shared__ __align__(16) _Float16 sBhi[256 * 32];   // 16 KB
    __shared__ __align__(16) _Float16 sBlo[256 * 32];   // 16 KB

    const int t = threadIdx.x;
    const int row0 = blockIdx.x * 64;

    // --- staging address precompute (linear LDS dest, pre-swizzled source) ---
    const int ar = t >> 2;            // A tile row 0..63
    const int ap = t & 3;             // 16B chunk position within 64B row
    const int ag = ap ^ ((ar >> 1) & 3);
    int arow = row0 + ar; if (arow > M - 1) arow = M - 1;
    const _Float16* aSrc = A + (long long)arow * K + ag * 8;
    char* aDst = (char*)sA + t * 16;

    const int bc0 = t >> 2;           // B tile row (out col) for issue 0
    const int gb = ap ^ ((bc0 >> 1) & 3);   // same for all 4 issues (64 | step)
    const _Float16* bhSrc = BThi + (long long)bc0 * K + gb * 8;
    const _Float16* blSrc = BTlo + (long long)bc0 * K + gb * 8;
    char* bhDst = (char*)sBhi + t * 16;
    char* blDst = (char*)sBlo + t * 16;

    // --- wave tiling ---
    const int w = t >> 6, lane = t & 63;
    const int wr = w >> 1, wc = w & 1;
    const int lrow = lane & 15, g = lane >> 4;

    unsigned int offA[2], offB[8];
    #pragma unroll
    for (int rt = 0; rt < 2; ++rt) {
        int r = wr * 32 + rt * 16 + lrow;
        offA[rt] = r * 64 + (g ^ ((r >> 1) & 3)) * 16;
    }
    #pragma unroll
    for (int ct = 0; ct < 8; ++ct) {
        int c = wc * 128 + ct * 16 + lrow;
        offB[ct] = c * 64 + (g ^ ((c >> 1) & 3)) * 16;
    }

    f32x4 acc[2][8];
    #pragma unroll
    for (int i = 0; i < 2; ++i)
        #pragma unroll
        for (int j = 0; j < 8; ++j)
            acc[i][j] = (f32x4){0.f, 0.f, 0.f, 0.f};

    for (int k0 = 0; k0 < K; k0 += 32) {
        __syncthreads();
        gload16(aSrc + k0, aDst);
        #pragma unroll
        for (int j = 0; j < 4; ++j) {
            gload16(bhSrc + (long long)j * 64 * K + k0, bhDst + j * 4096);
            gload16(blSrc + (long long)j * 64 * K + k0, blDst + j * 4096);
        }
        __syncthreads();

        half8 a[2], bh[8], bl[8];
        #pragma unroll
        for (int rt = 0; rt < 2; ++rt)
            a[rt] = *reinterpret_cast<const half8*>((const char*)sA + offA[rt]);
        #pragma unroll
        for (int ct = 0; ct < 8; ++ct) {
            bh[ct] = *reinterpret_cast<const half8*>((const char*)sBhi + offB[ct]);
            bl[ct] = *reinterpret_cast<const half8*>((const char*)sBlo + offB[ct]);
        }
        #pragma unroll
        for (int rt = 0; rt < 2; ++rt)
            #pragma unroll
            for (int ct = 0; ct < 8; ++ct) {
                acc[rt][ct] = __builtin_amdgcn_mfma_f32_16x16x32_f16(a[rt], bh[ct], acc[rt][ct], 0, 0, 0);
                acc[rt][ct] = __builtin_amdgcn_mfma_f32_16x16x32_f16(a[rt], bl[ct], acc[rt][ct], 0, 0, 0);
            }
    }

    // --- epilogue: bias + relu + f16 store.  C/D map: col=lane&15, row=g*4+j ---
    #pragma unroll
    for (int ct = 0; ct < 8; ++ct) {
        int col = wc * 128 + ct * 16 + lrow;
        float bb = bias[col];
        #pragma unroll
        for (int rt = 0; rt < 2; ++rt) {
            #pragma unroll
            for (int j = 0; j < 4; ++j) {
                int row = row0 + wr * 32 + rt * 16 + g * 4 + j;
                if (row < M) {
                    float v = acc[rt][ct][j] + bb;
                    if (doRelu) v = fmaxf(v, 0.f);
                    C[(long long)row * 256 + col] = (_Float16)v;
                }
            }
        }
    }
}

// ---------------------------------------------------------------------------
// K6: per-node dot with W4 [256] + b4 -> block partial sums (h3 is f16)
// ---------------------------------------------------------------------------
__global__ __launch_bounds__(256) void outdot_kernel(
    const _Float16* __restrict__ h3, const float* __restrict__ W4,
    const float* __restrict__ b4, float* __restrict__ partials)
{
    __shared__ float red[4];
    int lane = threadIdx.x & 63;
    int wid  = threadIdx.x >> 6;
    int wavesTotal = gridDim.x * 4;
    float local = 0.f;
    float4 w = *reinterpret_cast<const float4*>(&W4[lane * 4]);
    float bb = b4[0];
    for (int n = blockIdx.x * 4 + wid; n < N_NODES; n += wavesTotal) {
        union { uint2 u; _Float16 h[4]; } cv;
        cv.u = *reinterpret_cast<const uint2*>(&h3[(long long)n * 256 + lane * 4]);
        float d = (float)cv.h[0] * w.x + (float)cv.h[1] * w.y
                + (float)cv.h[2] * w.z + (float)cv.h[3] * w.w;
        #pragma unroll
        for (int off = 32; off > 0; off >>= 1) d += __shfl_xor(d, off, 64);
        if (lane == 0) local += d + bb;
    }
    if (lane == 0) red[wid] = local;
    __syncthreads();
    if (threadIdx.x == 0)
        partials[blockIdx.x] = red[0] + red[1] + red[2] + red[3];
}

__global__ __launch_bounds__(256) void final_kernel(
    const float* __restrict__ partials, int n, float* __restrict__ out)
{
    __shared__ float buf[256];
    float s = 0.f;
    for (int i = threadIdx.x; i < n; i += 256) s += partials[i];
    buf[threadIdx.x] = s;
    __syncthreads();
    for (int off = 128; off > 0; off >>= 1) {
        if (threadIdx.x < off) buf[threadIdx.x] += buf[threadIdx.x + off];
        __syncthreads();
    }
    if (threadIdx.x == 0) out[0] = buf[0] / (float)N_NODES;
}

// ---------------------------------------------------------------------------
extern "C" void kernel_launch(void* const* d_in, const int* in_sizes, int n_in,
                              void* d_out, int out_size, void* d_ws, size_t ws_size,
                              hipStream_t stream)
{
    const float* x   = (const float*)d_in[0];
    const float* pos = (const float*)d_in[1];
    const float* z   = (const float*)d_in[2];
    const int*   ei  = (const int*)d_in[3];
    const float* W1  = (const float*)d_in[4];
    const float* b1  = (const float*)d_in[5];
    const float* W2  = (const float*)d_in[6];
    const float* b2  = (const float*)d_in[7];
    const float* W3  = (const float*)d_in[8];
    const float* b3  = (const float*)d_in[9];
    const float* W4  = (const float*)d_in[10];
    const float* b4  = (const float*)d_in[11];
    float* out = (float*)d_out;

    char* ws = (char*)d_ws;
    float*    feats     = (float*)   (ws);                 // 51,200,000
    _Float16* h0        = (_Float16*)(ws +  51200000);     // 25,600,000
    _Float16* h1        = (_Float16*)(ws +  76800000);     // 51,200,000
    _Float16* h2        = (_Float16*)(ws + 128000000);     // 51,200,000
    _Float16* h3        = (_Float16*)(ws + 179200000);     // 51,200,000
    int*      counts    = (int*)     (ws + 230400000);     // 400,000
    int*      rowptr    = (int*)     (ws + 230800000);     // 400,004
    int*      cursor    = (int*)     (ws + 231200128);     // 400,000
    int*      sortedDst = (int*)     (ws + 231600128);     // 12,800,000
    int*      bsums     = (int*)     (ws + 244400128);     // ~1,600
    _Float16* WT1hi     = (_Float16*)(ws + 244401792);     // 65,536
    _Float16* WT1lo     = (_Float16*)(ws + 244467328);     // 65,536
    _Float16* WT2hi     = (_Float16*)(ws + 244532864);     // 131,072
    _Float16* WT2lo     = (_Float16*)(ws + 244663936);     // 131,072
    _Float16* WT3hi     = (_Float16*)(ws + 244795008);     // 131,072
    _Float16* WT3lo     = (_Float16*)(ws + 244926080);     // 131,072
    float*    partials  = (float*)   (ws + 245057152);     // 4,096

    // weight prep (independent of edge pipeline)
    wprep_kernel<<<(128 * 256 + 255) / 256, 256, 0, stream>>>(W1, 128, WT1hi, WT1lo);
    wprep_kernel<<<(256 * 256 + 255) / 256, 256, 0, stream>>>(W2, 256, WT2hi, WT2lo);
    wprep_kernel<<<(256 * 256 + 255) / 256, 256, 0, stream>>>(W3, 256, WT3hi, WT3lo);

    // K0 pack
    pack_kernel<<<(N_NODES * 128 + 255) / 256, 256, 0, stream>>>(x, pos, z, feats);

    // K1 histogram
    hipMemsetAsync(counts, 0, (size_t)N_NODES * sizeof(int), stream);
    hist_kernel<<<(N_EDGES + 255) / 256, 256, 0, stream>>>(ei, counts);

    // K2 multi-block scan
    blocksum_kernel<<<SCAN_BLOCKS, 256, 0, stream>>>(counts, bsums);
    scanbsums_kernel<<<1, 512, 0, stream>>>(bsums, rowptr);
    blockscan_kernel<<<SCAN_BLOCKS, 256, 0, stream>>>(counts, bsums, rowptr, cursor);

    // K3 CSR permute
    sortedges_kernel<<<(N_EDGES + 255) / 256, 256, 0, stream>>>(ei, cursor, sortedDst);

    // K4 aggregate + normalize -> h0 (f16)
    aggregate_kernel<<<(N_NODES * 64 + 255) / 256, 256, 0, stream>>>(
        rowptr, sortedDst, (const float2*)feats, h0);

    // K5 GEMMs (MFMA f16, hi/lo-split weights)
    int gblocks = (N_NODES + 63) / 64;
    gemm_f16_kernel<<<gblocks, 256, 0, stream>>>(h0, WT1hi, WT1lo, b1, h1, N_NODES, 128, 1);
    gemm_f16_kernel<<<gblocks, 256, 0, stream>>>(h1, WT2hi, WT2lo, b2, h2, N_NODES, 256, 1);
    gemm_f16_kernel<<<gblocks, 256, 0, stream>>>(h2, WT3hi, WT3lo, b3, h3, N_NODES, 256, 1);

    // K6 out dot + partial reduce
    outdot_kernel<<<1024, 256, 0, stream>>>(h3, W4, b4, partials);

    // K7 final mean
    final_kernel<<<1, 256, 0, stream>>>(partials, 1024, out);
}

// Round 4
// 650.068 us; speedup vs baseline: 2.8724x; 1.3689x over previous
//
#include <hip/hip_runtime.h>
#include <math.h>

#define N_NODES 100000
#define N_EDGES 3200000
#define SCAN_BLOCKS ((N_NODES + 255) / 256)   // 391
#define CPAD 16                               // counts padded to 1 per 64B line

typedef _Float16 half8 __attribute__((ext_vector_type(8)));
typedef float f32x4 __attribute__((ext_vector_type(4)));

__device__ __forceinline__ void gload16(const void* gsrc, void* ldst) {
    __builtin_amdgcn_global_load_lds(
        (const __attribute__((address_space(1))) unsigned int*)gsrc,
        (__attribute__((address_space(3))) unsigned int*)ldst,
        16, 0, 0);
}

// ---------------------------------------------------------------------------
// K0: pack feats[N,128] (f16) = concat(x[124], pos[3], z[1])
// ---------------------------------------------------------------------------
__global__ __launch_bounds__(256) void pack_kernel(
    const float* __restrict__ x, const float* __restrict__ pos,
    const float* __restrict__ z, _Float16* __restrict__ feats)
{
    int idx = blockIdx.x * blockDim.x + threadIdx.x;
    if (idx >= N_NODES * 128) return;
    int n = idx >> 7, f = idx & 127;
    float v;
    if (f < 124)      v = x[n * 124 + f];
    else if (f < 127) v = pos[n * 3 + (f - 124)];
    else              v = z[n];
    feats[idx] = (_Float16)v;
}

// ---------------------------------------------------------------------------
// weight prep: W[K,256] f32 -> WThi/WTlo [256,K] f16 (hi/lo split)
// ---------------------------------------------------------------------------
__global__ __launch_bounds__(256) void wprep_kernel(
    const float* __restrict__ W, int K,
    _Float16* __restrict__ WThi, _Float16* __restrict__ WTlo)
{
    int idx = blockIdx.x * blockDim.x + threadIdx.x;
    if (idx >= K * 256) return;
    int k = idx >> 8, c = idx & 255;
    float v = W[idx];
    _Float16 hi = (_Float16)v;
    _Float16 lo = (_Float16)(v - (float)hi);
    WThi[c * K + k] = hi;
    WTlo[c * K + k] = lo;
}

// ---------------------------------------------------------------------------
// K1: histogram of src + per-edge rank claim (padded counters: 1 per line)
// ---------------------------------------------------------------------------
__global__ __launch_bounds__(256) void hist_rank_kernel(
    const int* __restrict__ ei, int* __restrict__ counts16,
    int* __restrict__ rank)
{
    int e = blockIdx.x * blockDim.x + threadIdx.x;
    if (e >= N_EDGES) return;
    int src = __builtin_nontemporal_load(&ei[e]);
    int r = atomicAdd(&counts16[src * CPAD], 1);
    __builtin_nontemporal_store(r, &rank[e]);
}

// ---------------------------------------------------------------------------
// K2a/b/c: multi-block exclusive scan of padded counts -> rowptr
// ---------------------------------------------------------------------------
__global__ __launch_bounds__(256) void blocksum_kernel(
    const int* __restrict__ counts16, int* __restrict__ bsums)
{
    __shared__ int red[4];
    int i = blockIdx.x * 256 + threadIdx.x;
    int v = (i < N_NODES) ? counts16[i * CPAD] : 0;
    #pragma unroll
    for (int off = 32; off > 0; off >>= 1) v += __shfl_xor(v, off, 64);
    if ((threadIdx.x & 63) == 0) red[threadIdx.x >> 6] = v;
    __syncthreads();
    if (threadIdx.x == 0) bsums[blockIdx.x] = red[0] + red[1] + red[2] + red[3];
}

__global__ __launch_bounds__(512) void scanbsums_kernel(
    int* __restrict__ bsums, int* __restrict__ rowptr)
{
    __shared__ int s[512];
    int t = threadIdx.x;
    int v = (t < SCAN_BLOCKS) ? bsums[t] : 0;
    s[t] = v;
    __syncthreads();
    for (int off = 1; off < 512; off <<= 1) {
        int o = (t >= off) ? s[t - off] : 0;
        __syncthreads();
        s[t] += o;
        __syncthreads();
    }
    if (t < SCAN_BLOCKS) bsums[t] = s[t] - v;   // exclusive block offset
    if (t == SCAN_BLOCKS - 1) rowptr[N_NODES] = s[t];
}

__global__ __launch_bounds__(256) void blockscan_kernel(
    const int* __restrict__ counts16, const int* __restrict__ bsums,
    int* __restrict__ rowptr)
{
    __shared__ int s[256];
    int t = threadIdx.x;
    int i = blockIdx.x * 256 + t;
    int v = (i < N_NODES) ? counts16[i * CPAD] : 0;
    s[t] = v;
    __syncthreads();
    for (int off = 1; off < 256; off <<= 1) {
        int o = (t >= off) ? s[t - off] : 0;
        __syncthreads();
        s[t] += o;
        __syncthreads();
    }
    if (i < N_NODES) rowptr[i] = s[t] - v + bsums[blockIdx.x];
}

// ---------------------------------------------------------------------------
// K3: atomic-free CSR permute: sorted_dst[rowptr[src] + rank[e]] = dst
// ---------------------------------------------------------------------------
__global__ __launch_bounds__(256) void scatter_kernel(
    const int* __restrict__ ei, const int* __restrict__ rank,
    const int* __restrict__ rowptr, int* __restrict__ sorted_dst)
{
    int e = blockIdx.x * blockDim.x + threadIdx.x;
    if (e >= N_EDGES) return;
    int src = __builtin_nontemporal_load(&ei[e]);
    int dst = __builtin_nontemporal_load(&ei[N_EDGES + e]);
    int r   = __builtin_nontemporal_load(&rank[e]);
    int p = rowptr[src] + r;
    __builtin_nontemporal_store(dst, &sorted_dst[p]);
}

// ---------------------------------------------------------------------------
// K4: aggregate (f16 gather) + fused L2 normalize -> h0 (f16). 1 wave/node.
// ---------------------------------------------------------------------------
__global__ __launch_bounds__(256) void aggregate_kernel(
    const int* __restrict__ rowptr, const int* __restrict__ sorted_dst,
    const unsigned int* __restrict__ feats_u,   // half2 per lane
    _Float16* __restrict__ h0)
{
    int node = (blockIdx.x * blockDim.x + threadIdx.x) >> 6;
    int lane = threadIdx.x & 63;
    if (node >= N_NODES) return;
    int start = rowptr[node], end = rowptr[node + 1];
    float ax = 0.f, ay = 0.f;
    int i = start;
    int dst_next = (i < end) ? sorted_dst[i] : 0;
    while (i < end) {
        int dst = dst_next;
        ++i;
        if (i < end) dst_next = sorted_dst[i];
        union { unsigned int u; _Float16 h[2]; } cv;
        cv.u = feats_u[(long long)dst * 64 + lane];
        ax += (float)cv.h[0]; ay += (float)cv.h[1];
    }
    float ss = ax * ax + ay * ay;
    #pragma unroll
    for (int off = 32; off > 0; off >>= 1) ss += __shfl_xor(ss, off, 64);
    float inv = 1.0f / sqrtf(ss);
    union { unsigned int u; _Float16 h[2]; } ov;
    ov.h[0] = (_Float16)(ax * inv);
    ov.h[1] = (_Float16)(ay * inv);
    *reinterpret_cast<unsigned int*>(&h0[(long long)node * 128 + lane * 2]) = ov.u;
}

// ---------------------------------------------------------------------------
// K5: MFMA GEMM  C[M,256] = relu(A[M,K] @ (WThi+WTlo)^T + bias)
// BM=64, BN=256, BK=32; 256 threads = 4 waves (2x2)
// fuseOut: skip C store; dot rows with W4, block-reduce into partials[blk]
// ---------------------------------------------------------------------------
__global__ __launch_bounds__(256) void gemm_f16_kernel(
    const _Float16* __restrict__ A,     // [M][K]
    const _Float16* __restrict__ BThi,  // [256][K]
    const _Float16* __restrict__ BTlo,  // [256][K]
    const float* __restrict__ bias,     // [256]
    _Float16* __restrict__ C,           // [M][256] (unused if fuseOut)
    const float* __restrict__ W4,       // [256]    (used if fuseOut)
    float* __restrict__ partials,       // [gridDim.x] (used if fuseOut)
    int M, int K, int fuseOut)
{
    __shared__ __align__(16) _Float16 sA[64 * 32];      // 4 KB
    __shared__ __align__(16) _Float16 sBhi[256 * 32];   // 16 KB
    __shared__ __align__(16) _Float16 sBlo[256 * 32];   // 16 KB
    __shared__ float redf[4];

    const int t = threadIdx.x;
    const int row0 = blockIdx.x * 64;

    // staging: linear LDS dest, pre-swizzled global source
    const int ar = t >> 2;
    const int ap = t & 3;
    const int ag = ap ^ ((ar >> 1) & 3);
    int arow = row0 + ar; if (arow > M - 1) arow = M - 1;
    const _Float16* aSrc = A + (long long)arow * K + ag * 8;
    char* aDst = (char*)sA + t * 16;

    const int bc0 = t >> 2;
    const int gb = ap ^ ((bc0 >> 1) & 3);
    const _Float16* bhSrc = BThi + (long long)bc0 * K + gb * 8;
    const _Float16* blSrc = BTlo + (long long)bc0 * K + gb * 8;
    char* bhDst = (char*)sBhi + t * 16;
    char* blDst = (char*)sBlo + t * 16;

    const int w = t >> 6, lane = t & 63;
    const int wr = w >> 1, wc = w & 1;
    const int lrow = lane & 15, g = lane >> 4;

    unsigned int offA[2], offB[8];
    #pragma unroll
    for (int rt = 0; rt < 2; ++rt) {
        int r = wr * 32 + rt * 16 + lrow;
        offA[rt] = r * 64 + (g ^ ((r >> 1) & 3)) * 16;
    }
    #pragma unroll
    for (int ct = 0; ct < 8; ++ct) {
        int c = wc * 128 + ct * 16 + lrow;
        offB[ct] = c * 64 + (g ^ ((c >> 1) & 3)) * 16;
    }

    f32x4 acc[2][8];
    #pragma unroll
    for (int i = 0; i < 2; ++i)
        #pragma unroll
        for (int j = 0; j < 8; ++j)
            acc[i][j] = (f32x4){0.f, 0.f, 0.f, 0.f};

    for (int k0 = 0; k0 < K; k0 += 32) {
        __syncthreads();
        gload16(aSrc + k0, aDst);
        #pragma unroll
        for (int j = 0; j < 4; ++j) {
            gload16(bhSrc + (long long)j * 64 * K + k0, bhDst + j * 4096);
            gload16(blSrc + (long long)j * 64 * K + k0, blDst + j * 4096);
        }
        __syncthreads();

        half8 a[2], bh[8], bl[8];
        #pragma unroll
        for (int rt = 0; rt < 2; ++rt)
            a[rt] = *reinterpret_cast<const half8*>((const char*)sA + offA[rt]);
        #pragma unroll
        for (int ct = 0; ct < 8; ++ct) {
            bh[ct] = *reinterpret_cast<const half8*>((const char*)sBhi + offB[ct]);
            bl[ct] = *reinterpret_cast<const half8*>((const char*)sBlo + offB[ct]);
        }
        #pragma unroll
        for (int rt = 0; rt < 2; ++rt)
            #pragma unroll
            for (int ct = 0; ct < 8; ++ct) {
                acc[rt][ct] = __builtin_amdgcn_mfma_f32_16x16x32_f16(a[rt], bh[ct], acc[rt][ct], 0, 0, 0);
                acc[rt][ct] = __builtin_amdgcn_mfma_f32_16x16x32_f16(a[rt], bl[ct], acc[rt][ct], 0, 0, 0);
            }
    }

    // epilogue.  C/D map: col = lane&15 (lrow), row = g*4 + j
    if (!fuseOut) {
        #pragma unroll
        for (int ct = 0; ct < 8; ++ct) {
            int col = wc * 128 + ct * 16 + lrow;
            float bb = bias[col];
            #pragma unroll
            for (int rt = 0; rt < 2; ++rt) {
                #pragma unroll
                for (int j = 0; j < 4; ++j) {
                    int row = row0 + wr * 32 + rt * 16 + g * 4 + j;
                    if (row < M) {
                        float v = fmaxf(acc[rt][ct][j] + bb, 0.f);
                        C[(long long)row * 256 + col] = (_Float16)v;
                    }
                }
            }
        }
    } else {
        float s = 0.f;
        #pragma unroll
        for (int ct = 0; ct < 8; ++ct) {
            int col = wc * 128 + ct * 16 + lrow;
            float bb = bias[col];
            float w4 = W4[col];
            #pragma unroll
            for (int rt = 0; rt < 2; ++rt) {
                #pragma unroll
                for (int j = 0; j < 4; ++j) {
                    int row = row0 + wr * 32 + rt * 16 + g * 4 + j;
                    if (row < M) {
                        float v = fmaxf(acc[rt][ct][j] + bb, 0.f);
                        s += v * w4;
                    }
                }
            }
        }
        #pragma unroll
        for (int off = 32; off > 0; off >>= 1) s += __shfl_xor(s, off, 64);
        if (lane == 0) redf[w] = s;
        __syncthreads();
        if (t == 0) partials[blockIdx.x] = redf[0] + redf[1] + redf[2] + redf[3];
    }
}

// ---------------------------------------------------------------------------
// K7: final mean: out = sum(partials)/N + b4
// ---------------------------------------------------------------------------
__global__ __launch_bounds__(256) void final_kernel(
    const float* __restrict__ partials, int n,
    const float* __restrict__ b4, float* __restrict__ out)
{
    __shared__ float buf[256];
    float s = 0.f;
    for (int i = threadIdx.x; i < n; i += 256) s += partials[i];
    buf[threadIdx.x] = s;
    __syncthreads();
    for (int off = 128; off > 0; off >>= 1) {
        if (threadIdx.x < off) buf[threadIdx.x] += buf[threadIdx.x + off];
        __syncthreads();
    }
    if (threadIdx.x == 0) out[0] = buf[0] / (float)N_NODES + b4[0];
}

// ---------------------------------------------------------------------------
extern "C" void kernel_launch(void* const* d_in, const int* in_sizes, int n_in,
                              void* d_out, int out_size, void* d_ws, size_t ws_size,
                              hipStream_t stream)
{
    const float* x   = (const float*)d_in[0];
    const float* pos = (const float*)d_in[1];
    const float* z   = (const float*)d_in[2];
    const int*   ei  = (const int*)d_in[3];
    const float* W1  = (const float*)d_in[4];
    const float* b1  = (const float*)d_in[5];
    const float* W2  = (const float*)d_in[6];
    const float* b2  = (const float*)d_in[7];
    const float* W3  = (const float*)d_in[8];
    const float* b3  = (const float*)d_in[9];
    const float* W4  = (const float*)d_in[10];
    const float* b4  = (const float*)d_in[11];
    float* out = (float*)d_out;

    char* ws = (char*)d_ws;
    _Float16* feats     = (_Float16*)(ws);                 //  25,600,000
    _Float16* h0        = (_Float16*)(ws +  25600000);     //  25,600,000
    _Float16* h1        = (_Float16*)(ws +  51200000);     //  51,200,000
    _Float16* h2        = (_Float16*)(ws + 102400000);     //  51,200,000
    int*      counts16  = (int*)     (ws + 153600000);     //   6,400,000
    int*      rowptr    = (int*)     (ws + 160000000);     //     400,004
    int*      rank      = (int*)     (ws + 160400064);     //  12,800,000
    int*      sortedDst = (int*)     (ws + 173200064);     //  12,800,000
    int*      bsums     = (int*)     (ws + 186000064);     //      ~1,600
    _Float16* WT1hi     = (_Float16*)(ws + 186001728);     //      65,536
    _Float16* WT1lo     = (_Float16*)(ws + 186067264);     //      65,536
    _Float16* WT2hi     = (_Float16*)(ws + 186132800);     //     131,072
    _Float16* WT2lo     = (_Float16*)(ws + 186263872);     //     131,072
    _Float16* WT3hi     = (_Float16*)(ws + 186394944);     //     131,072
    _Float16* WT3lo     = (_Float16*)(ws + 186526016);     //     131,072
    float*    partials  = (float*)   (ws + 186657088);     //       6,252

    const int gblocks = (N_NODES + 63) / 64;   // 1563

    // weight prep
    wprep_kernel<<<(128 * 256 + 255) / 256, 256, 0, stream>>>(W1, 128, WT1hi, WT1lo);
    wprep_kernel<<<(256 * 256 + 255) / 256, 256, 0, stream>>>(W2, 256, WT2hi, WT2lo);
    wprep_kernel<<<(256 * 256 + 255) / 256, 256, 0, stream>>>(W3, 256, WT3hi, WT3lo);

    // pack features (f16)
    pack_kernel<<<(N_NODES * 128 + 255) / 256, 256, 0, stream>>>(x, pos, z, feats);

    // histogram + rank claim
    hipMemsetAsync(counts16, 0, (size_t)N_NODES * CPAD * sizeof(int), stream);
    hist_rank_kernel<<<(N_EDGES + 255) / 256, 256, 0, stream>>>(ei, counts16, rank);

    // scan -> rowptr
    blocksum_kernel<<<SCAN_BLOCKS, 256, 0, stream>>>(counts16, bsums);
    scanbsums_kernel<<<1, 512, 0, stream>>>(bsums, rowptr);
    blockscan_kernel<<<SCAN_BLOCKS, 256, 0, stream>>>(counts16, bsums, rowptr);

    // atomic-free CSR permute
    scatter_kernel<<<(N_EDGES + 255) / 256, 256, 0, stream>>>(ei, rank, rowptr, sortedDst);

    // aggregate + normalize -> h0 (f16)
    aggregate_kernel<<<(N_NODES * 64 + 255) / 256, 256, 0, stream>>>(
        rowptr, sortedDst, (const unsigned int*)feats, h0);

    // GEMMs (MFMA f16, hi/lo-split weights); GEMM3 fused with out-dot
    gemm_f16_kernel<<<gblocks, 256, 0, stream>>>(h0, WT1hi, WT1lo, b1, h1, nullptr, nullptr, N_NODES, 128, 0);
    gemm_f16_kernel<<<gblocks, 256, 0, stream>>>(h1, WT2hi, WT2lo, b2, h2, nullptr, nullptr, N_NODES, 256, 0);
    gemm_f16_kernel<<<gblocks, 256, 0, stream>>>(h2, WT3hi, WT3lo, b3, nullptr, W4, partials, N_NODES, 256, 1);

    // final mean
    final_kernel<<<1, 256, 0, stream>>>(partials, gblocks, b4, out);
}

// Round 5
// 539.050 us; speedup vs baseline: 3.4640x; 1.2060x over previous
//
#include <hip/hip_runtime.h>
#include <math.h>

#define N_NODES 100000
#define N_EDGES 3200000
#define SCAN_BLOCKS ((N_NODES + 255) / 256)   // 391
#define CPAD 16                               // counts padded to 1 per 64B line

typedef _Float16 half8 __attribute__((ext_vector_type(8)));
typedef float f32x4 __attribute__((ext_vector_type(4)));

__device__ __forceinline__ void gload16(const void* gsrc, void* ldst) {
    __builtin_amdgcn_global_load_lds(
        (const __attribute__((address_space(1))) unsigned int*)gsrc,
        (__attribute__((address_space(3))) unsigned int*)ldst,
        16, 0, 0);
}

// ---------------------------------------------------------------------------
// K0: pack feats[N,128] (f16) = concat(x[124], pos[3], z[1])
// ---------------------------------------------------------------------------
__global__ __launch_bounds__(256) void pack_kernel(
    const float* __restrict__ x, const float* __restrict__ pos,
    const float* __restrict__ z, _Float16* __restrict__ feats)
{
    int idx = blockIdx.x * blockDim.x + threadIdx.x;
    if (idx >= N_NODES * 128) return;
    int n = idx >> 7, f = idx & 127;
    float v;
    if (f < 124)      v = x[n * 124 + f];
    else if (f < 127) v = pos[n * 3 + (f - 124)];
    else              v = z[n];
    feats[idx] = (_Float16)v;
}

// ---------------------------------------------------------------------------
// weight prep: W[K,256] f32 -> WT [256,K] f16
// ---------------------------------------------------------------------------
__global__ __launch_bounds__(256) void wprep_kernel(
    const float* __restrict__ W, int K, _Float16* __restrict__ WT)
{
    int idx = blockIdx.x * blockDim.x + threadIdx.x;
    if (idx >= K * 256) return;
    int k = idx >> 8, c = idx & 255;
    WT[c * K + k] = (_Float16)W[idx];
}

// ---------------------------------------------------------------------------
// K1: histogram of src + per-edge rank claim (padded counters: 1 per line)
// ---------------------------------------------------------------------------
__global__ __launch_bounds__(256) void hist_rank_kernel(
    const int* __restrict__ ei, int* __restrict__ counts16,
    int* __restrict__ rank)
{
    int e = blockIdx.x * blockDim.x + threadIdx.x;
    if (e >= N_EDGES) return;
    int src = __builtin_nontemporal_load(&ei[e]);
    int r = atomicAdd(&counts16[src * CPAD], 1);
    __builtin_nontemporal_store(r, &rank[e]);
}

// ---------------------------------------------------------------------------
// K2a/b/c: multi-block exclusive scan of padded counts -> rowptr
// ---------------------------------------------------------------------------
__global__ __launch_bounds__(256) void blocksum_kernel(
    const int* __restrict__ counts16, int* __restrict__ bsums)
{
    __shared__ int red[4];
    int i = blockIdx.x * 256 + threadIdx.x;
    int v = (i < N_NODES) ? counts16[i * CPAD] : 0;
    #pragma unroll
    for (int off = 32; off > 0; off >>= 1) v += __shfl_xor(v, off, 64);
    if ((threadIdx.x & 63) == 0) red[threadIdx.x >> 6] = v;
    __syncthreads();
    if (threadIdx.x == 0) bsums[blockIdx.x] = red[0] + red[1] + red[2] + red[3];
}

__global__ __launch_bounds__(512) void scanbsums_kernel(
    int* __restrict__ bsums, int* __restrict__ rowptr)
{
    __shared__ int s[512];
    int t = threadIdx.x;
    int v = (t < SCAN_BLOCKS) ? bsums[t] : 0;
    s[t] = v;
    __syncthreads();
    for (int off = 1; off < 512; off <<= 1) {
        int o = (t >= off) ? s[t - off] : 0;
        __syncthreads();
        s[t] += o;
        __syncthreads();
    }
    if (t < SCAN_BLOCKS) bsums[t] = s[t] - v;   // exclusive block offset
    if (t == SCAN_BLOCKS - 1) rowptr[N_NODES] = s[t];
}

__global__ __launch_bounds__(256) void blockscan_kernel(
    const int* __restrict__ counts16, const int* __restrict__ bsums,
    int* __restrict__ rowptr)
{
    __shared__ int s[256];
    int t = threadIdx.x;
    int i = blockIdx.x * 256 + t;
    int v = (i < N_NODES) ? counts16[i * CPAD] : 0;
    s[t] = v;
    __syncthreads();
    for (int off = 1; off < 256; off <<= 1) {
        int o = (t >= off) ? s[t - off] : 0;
        __syncthreads();
        s[t] += o;
        __syncthreads();
    }
    if (i < N_NODES) rowptr[i] = s[t] - v + bsums[blockIdx.x];
}

// ---------------------------------------------------------------------------
// K3: atomic-free CSR permute: sorted_dst[rowptr[src] + rank[e]] = dst
// ---------------------------------------------------------------------------
__global__ __launch_bounds__(256) void scatter_kernel(
    const int* __restrict__ ei, const int* __restrict__ rank,
    const int* __restrict__ rowptr, int* __restrict__ sorted_dst)
{
    int e = blockIdx.x * blockDim.x + threadIdx.x;
    if (e >= N_EDGES) return;
    int src = __builtin_nontemporal_load(&ei[e]);
    int dst = __builtin_nontemporal_load(&ei[N_EDGES + e]);
    int r   = __builtin_nontemporal_load(&rank[e]);
    int p = rowptr[src] + r;
    __builtin_nontemporal_store(dst, &sorted_dst[p]);
}

// ---------------------------------------------------------------------------
// K4: aggregate + fused L2 normalize -> h0 (f16). One wave per node.
// Lane loads uint2 (4 f16); 32 lanes cover a 128-feat row; the wave's two
// halves process two edges at once; main loop does 4 edges/iter.
// ---------------------------------------------------------------------------
__global__ __launch_bounds__(256) void aggregate_kernel(
    const int* __restrict__ rowptr, const int* __restrict__ sorted_dst,
    const uint2* __restrict__ featsU2,   // [N][32] : 4 f16 each
    _Float16* __restrict__ h0)
{
    int node = (blockIdx.x * blockDim.x + threadIdx.x) >> 6;
    int lane = threadIdx.x & 63;
    if (node >= N_NODES) return;
    const int h = lane >> 5;        // half 0/1
    const int s = lane & 31;        // covers features 4s..4s+3
    int start = rowptr[node], end = rowptr[node + 1];
    float a0 = 0.f, a1 = 0.f, a2 = 0.f, a3 = 0.f;
    union { unsigned int u; _Float16 f[2]; } c;
    int i = start;
    for (; i + 4 <= end; i += 4) {
        int d0 = sorted_dst[i + h];
        int d1 = sorted_dst[i + 2 + h];
        uint2 u0 = featsU2[(long long)d0 * 32 + s];
        uint2 u1 = featsU2[(long long)d1 * 32 + s];
        c.u = u0.x; a0 += (float)c.f[0]; a1 += (float)c.f[1];
        c.u = u0.y; a2 += (float)c.f[0]; a3 += (float)c.f[1];
        c.u = u1.x; a0 += (float)c.f[0]; a1 += (float)c.f[1];
        c.u = u1.y; a2 += (float)c.f[0]; a3 += (float)c.f[1];
    }
    if (i + 2 <= end) {
        int d = sorted_dst[i + h];
        uint2 u = featsU2[(long long)d * 32 + s];
        c.u = u.x; a0 += (float)c.f[0]; a1 += (float)c.f[1];
        c.u = u.y; a2 += (float)c.f[0]; a3 += (float)c.f[1];
        i += 2;
    }
    if (i < end && h == 0) {
        int d = sorted_dst[i];
        uint2 u = featsU2[(long long)d * 32 + s];
        c.u = u.x; a0 += (float)c.f[0]; a1 += (float)c.f[1];
        c.u = u.y; a2 += (float)c.f[0]; a3 += (float)c.f[1];
    }
    // merge the two halves (both end holding the full sum)
    a0 += __shfl_xor(a0, 32, 64);
    a1 += __shfl_xor(a1, 32, 64);
    a2 += __shfl_xor(a2, 32, 64);
    a3 += __shfl_xor(a3, 32, 64);
    float ss = a0 * a0 + a1 * a1 + a2 * a2 + a3 * a3;
    #pragma unroll
    for (int off = 16; off > 0; off >>= 1) ss += __shfl_xor(ss, off, 64);
    float inv = 1.0f / sqrtf(ss);
    if (h == 0) {
        union { uint2 u; _Float16 f[4]; } o;
        o.f[0] = (_Float16)(a0 * inv); o.f[1] = (_Float16)(a1 * inv);
        o.f[2] = (_Float16)(a2 * inv); o.f[3] = (_Float16)(a3 * inv);
        *reinterpret_cast<uint2*>(&h0[(long long)node * 128 + s * 4]) = o.u;
    }
}

// ---------------------------------------------------------------------------
// K5: MFMA GEMM  C[M,256] = relu(A[M,K] @ WT^T + bias), f16 in/out
// BM=64, BN=256, BK=32; 256 threads = 4 waves (2x2)
// fuseOut: skip C store; dot rows with W4, block-reduce into partials[blk]
// ---------------------------------------------------------------------------
__global__ __launch_bounds__(256) void gemm_f16_kernel(
    const _Float16* __restrict__ A,     // [M][K]
    const _Float16* __restrict__ BT,    // [256][K]
    const float* __restrict__ bias,     // [256]
    _Float16* __restrict__ C,           // [M][256] (unused if fuseOut)
    const float* __restrict__ W4,       // [256]    (used if fuseOut)
    float* __restrict__ partials,       // [gridDim.x] (used if fuseOut)
    int M, int K, int fuseOut)
{
    __shared__ __align__(16) _Float16 sA[64 * 32];      // 4 KB
    __shared__ __align__(16) _Float16 sB[256 * 32];     // 16 KB
    __shared__ float redf[4];

    const int t = threadIdx.x;
    const int row0 = blockIdx.x * 64;

    // staging: linear LDS dest, pre-swizzled global source
    const int ar = t >> 2;
    const int ap = t & 3;
    const int ag = ap ^ ((ar >> 1) & 3);
    int arow = row0 + ar; if (arow > M - 1) arow = M - 1;
    const _Float16* aSrc = A + (long long)arow * K + ag * 8;
    char* aDst = (char*)sA + t * 16;

    const int bc0 = t >> 2;
    const int gb = ap ^ ((bc0 >> 1) & 3);
    const _Float16* bSrc = BT + (long long)bc0 * K + gb * 8;
    char* bDst = (char*)sB + t * 16;

    const int w = t >> 6, lane = t & 63;
    const int wr = w >> 1, wc = w & 1;
    const int lrow = lane & 15, g = lane >> 4;

    unsigned int offA[2], offB[8];
    #pragma unroll
    for (int rt = 0; rt < 2; ++rt) {
        int r = wr * 32 + rt * 16 + lrow;
        offA[rt] = r * 64 + (g ^ ((r >> 1) & 3)) * 16;
    }
    #pragma unroll
    for (int ct = 0; ct < 8; ++ct) {
        int cidx = wc * 128 + ct * 16 + lrow;
        offB[ct] = cidx * 64 + (g ^ ((cidx >> 1) & 3)) * 16;
    }

    f32x4 acc[2][8];
    #pragma unroll
    for (int i = 0; i < 2; ++i)
        #pragma unroll
        for (int j = 0; j < 8; ++j)
            acc[i][j] = (f32x4){0.f, 0.f, 0.f, 0.f};

    for (int k0 = 0; k0 < K; k0 += 32) {
        __syncthreads();
        gload16(aSrc + k0, aDst);
        #pragma unroll
        for (int j = 0; j < 4; ++j)
            gload16(bSrc + (long long)j * 64 * K + k0, bDst + j * 4096);
        __syncthreads();

        half8 a[2], b[8];
        #pragma unroll
        for (int rt = 0; rt < 2; ++rt)
            a[rt] = *reinterpret_cast<const half8*>((const char*)sA + offA[rt]);
        #pragma unroll
        for (int ct = 0; ct < 8; ++ct)
            b[ct] = *reinterpret_cast<const half8*>((const char*)sB + offB[ct]);
        #pragma unroll
        for (int rt = 0; rt < 2; ++rt)
            #pragma unroll
            for (int ct = 0; ct < 8; ++ct)
                acc[rt][ct] = __builtin_amdgcn_mfma_f32_16x16x32_f16(a[rt], b[ct], acc[rt][ct], 0, 0, 0);
    }

    // epilogue.  C/D map: col = lane&15 (lrow), row = g*4 + j
    if (!fuseOut) {
        #pragma unroll
        for (int ct = 0; ct < 8; ++ct) {
            int col = wc * 128 + ct * 16 + lrow;
            float bb = bias[col];
            #pragma unroll
            for (int rt = 0; rt < 2; ++rt) {
                #pragma unroll
                for (int j = 0; j < 4; ++j) {
                    int row = row0 + wr * 32 + rt * 16 + g * 4 + j;
                    if (row < M) {
                        float v = fmaxf(acc[rt][ct][j] + bb, 0.f);
                        C[(long long)row * 256 + col] = (_Float16)v;
                    }
                }
            }
        }
    } else {
        float sum = 0.f;
        #pragma unroll
        for (int ct = 0; ct < 8; ++ct) {
            int col = wc * 128 + ct * 16 + lrow;
            float bb = bias[col];
            float w4 = W4[col];
            #pragma unroll
            for (int rt = 0; rt < 2; ++rt) {
                #pragma unroll
                for (int j = 0; j < 4; ++j) {
                    int row = row0 + wr * 32 + rt * 16 + g * 4 + j;
                    if (row < M) {
                        float v = fmaxf(acc[rt][ct][j] + bb, 0.f);
                        sum += v * w4;
                    }
                }
            }
        }
        #pragma unroll
        for (int off = 32; off > 0; off >>= 1) sum += __shfl_xor(sum, off, 64);
        if (lane == 0) redf[w] = sum;
        __syncthreads();
        if (t == 0) partials[blockIdx.x] = redf[0] + redf[1] + redf[2] + redf[3];
    }
}

// ---------------------------------------------------------------------------
// K7: final mean: out = sum(partials)/N + b4
// ---------------------------------------------------------------------------
__global__ __launch_bounds__(256) void final_kernel(
    const float* __restrict__ partials, int n,
    const float* __restrict__ b4, float* __restrict__ out)
{
    __shared__ float buf[256];
    float s = 0.f;
    for (int i = threadIdx.x; i < n; i += 256) s += partials[i];
    buf[threadIdx.x] = s;
    __syncthreads();
    for (int off = 128; off > 0; off >>= 1) {
        if (threadIdx.x < off) buf[threadIdx.x] += buf[threadIdx.x + off];
        __syncthreads();
    }
    if (threadIdx.x == 0) out[0] = buf[0] / (float)N_NODES + b4[0];
}

// ---------------------------------------------------------------------------
extern "C" void kernel_launch(void* const* d_in, const int* in_sizes, int n_in,
                              void* d_out, int out_size, void* d_ws, size_t ws_size,
                              hipStream_t stream)
{
    const float* x   = (const float*)d_in[0];
    const float* pos = (const float*)d_in[1];
    const float* z   = (const float*)d_in[2];
    const int*   ei  = (const int*)d_in[3];
    const float* W1  = (const float*)d_in[4];
    const float* b1  = (const float*)d_in[5];
    const float* W2  = (const float*)d_in[6];
    const float* b2  = (const float*)d_in[7];
    const float* W3  = (const float*)d_in[8];
    const float* b3  = (const float*)d_in[9];
    const float* W4  = (const float*)d_in[10];
    const float* b4  = (const float*)d_in[11];
    float* out = (float*)d_out;

    char* ws = (char*)d_ws;
    _Float16* feats     = (_Float16*)(ws);                 //  25,600,000
    _Float16* h0        = (_Float16*)(ws +  25600000);     //  25,600,000
    _Float16* h1        = (_Float16*)(ws +  51200000);     //  51,200,000
    _Float16* h2        = (_Float16*)(ws + 102400000);     //  51,200,000
    int*      counts16  = (int*)     (ws + 153600000);     //   6,400,000
    int*      rowptr    = (int*)     (ws + 160000000);     //     400,004
    int*      rank      = (int*)     (ws + 160400064);     //  12,800,000
    int*      sortedDst = (int*)     (ws + 173200064);     //  12,800,000
    int*      bsums     = (int*)     (ws + 186000064);     //      ~1,600
    _Float16* WT1       = (_Float16*)(ws + 186001728);     //      65,536
    _Float16* WT2       = (_Float16*)(ws + 186067264);     //     131,072
    _Float16* WT3       = (_Float16*)(ws + 186198336);     //     131,072
    float*    partials  = (float*)   (ws + 186329408);     //       6,252

    const int gblocks = (N_NODES + 63) / 64;   // 1563

    // weight prep
    wprep_kernel<<<(128 * 256 + 255) / 256, 256, 0, stream>>>(W1, 128, WT1);
    wprep_kernel<<<(256 * 256 + 255) / 256, 256, 0, stream>>>(W2, 256, WT2);
    wprep_kernel<<<(256 * 256 + 255) / 256, 256, 0, stream>>>(W3, 256, WT3);

    // pack features (f16)
    pack_kernel<<<(N_NODES * 128 + 255) / 256, 256, 0, stream>>>(x, pos, z, feats);

    // histogram + rank claim
    hipMemsetAsync(counts16, 0, (size_t)N_NODES * CPAD * sizeof(int), stream);
    hist_rank_kernel<<<(N_EDGES + 255) / 256, 256, 0, stream>>>(ei, counts16, rank);

    // scan -> rowptr
    blocksum_kernel<<<SCAN_BLOCKS, 256, 0, stream>>>(counts16, bsums);
    scanbsums_kernel<<<1, 512, 0, stream>>>(bsums, rowptr);
    blockscan_kernel<<<SCAN_BLOCKS, 256, 0, stream>>>(counts16, bsums, rowptr);

    // atomic-free CSR permute
    scatter_kernel<<<(N_EDGES + 255) / 256, 256, 0, stream>>>(ei, rank, rowptr, sortedDst);

    // aggregate + normalize -> h0 (f16)
    aggregate_kernel<<<(N_NODES * 64 + 255) / 256, 256, 0, stream>>>(
        rowptr, sortedDst, (const uint2*)feats, h0);

    // GEMMs (MFMA f16); GEMM3 fused with out-dot
    gemm_f16_kernel<<<gblocks, 256, 0, stream>>>(h0, WT1, b1, h1, nullptr, nullptr, N_NODES, 128, 0);
    gemm_f16_kernel<<<gblocks, 256, 0, stream>>>(h1, WT2, b2, h2, nullptr, nullptr, N_NODES, 256, 0);
    gemm_f16_kernel<<<gblocks, 256, 0, stream>>>(h2, WT3, b3, nullptr, W4, partials, N_NODES, 256, 1);

    // final mean
    final_kernel<<<1, 256, 0, stream>>>(partials, gblocks, b4, out);
}

// Round 6
// 525.719 us; speedup vs baseline: 3.5518x; 1.0254x over previous
//
#include <hip/hip_runtime.h>
#include <math.h>

#define N_NODES 100000
#define N_EDGES 3200000
#define SCAN_BLOCKS ((N_NODES + 255) / 256)   // 391
#define NREP 8                                 // one counter replica per XCD
#define RPAD 4                                 // 16B per counter (4 ints)

typedef _Float16 half8 __attribute__((ext_vector_type(8)));
typedef float f32x4 __attribute__((ext_vector_type(4)));

__device__ __forceinline__ void gload16(const void* gsrc, void* ldst) {
    __builtin_amdgcn_global_load_lds(
        (const __attribute__((address_space(1))) unsigned int*)gsrc,
        (__attribute__((address_space(3))) unsigned int*)ldst,
        16, 0, 0);
}

__device__ __forceinline__ int xcc_id() {
    int x;
    asm("s_getreg_b32 %0, hwreg(HW_REG_XCC_ID)" : "=s"(x));
    return x & (NREP - 1);
}

// ---------------------------------------------------------------------------
// K0: pack feats[N,128] (f16) = concat(x[124], pos[3], z[1])
// ---------------------------------------------------------------------------
__global__ __launch_bounds__(256) void pack_kernel(
    const float* __restrict__ x, const float* __restrict__ pos,
    const float* __restrict__ z, _Float16* __restrict__ feats)
{
    int idx = blockIdx.x * blockDim.x + threadIdx.x;
    if (idx >= N_NODES * 128) return;
    int n = idx >> 7, f = idx & 127;
    float v;
    if (f < 124)      v = x[n * 124 + f];
    else if (f < 127) v = pos[n * 3 + (f - 124)];
    else              v = z[n];
    feats[idx] = (_Float16)v;
}

// ---------------------------------------------------------------------------
// weight prep: W[K,256] f32 -> WT [256,K] f16
// ---------------------------------------------------------------------------
__global__ __launch_bounds__(256) void wprep_kernel(
    const float* __restrict__ W, int K, _Float16* __restrict__ WT)
{
    int idx = blockIdx.x * blockDim.x + threadIdx.x;
    if (idx >= K * 256) return;
    int k = idx >> 8, c = idx & 255;
    WT[c * K + k] = (_Float16)W[idx];
}

// ---------------------------------------------------------------------------
// K1: histogram + rank claim on XCD-local replica counters.
// rank packs replica id in bits 24+.
// ---------------------------------------------------------------------------
__global__ __launch_bounds__(256) void hist_rank_kernel(
    const int* __restrict__ ei, int* __restrict__ rcnt,
    int* __restrict__ rank)
{
    int e = blockIdx.x * blockDim.x + threadIdx.x;
    if (e >= N_EDGES) return;
    int rep = xcc_id();
    int src = __builtin_nontemporal_load(&ei[e]);
    int r = __hip_atomic_fetch_add(&rcnt[(rep * N_NODES + src) * RPAD], 1,
                                   __ATOMIC_RELAXED, __HIP_MEMORY_SCOPE_WORKGROUP);
    __builtin_nontemporal_store(r | (rep << 24), &rank[e]);
}

// ---------------------------------------------------------------------------
// K2: per-node replica-offset scan: repOff[r][n] = sum_{r'<r} cnt[r'][n];
//     totals[n] = sum_r cnt[r][n]
// ---------------------------------------------------------------------------
__global__ __launch_bounds__(256) void repscan_kernel(
    const int* __restrict__ rcnt, int* __restrict__ repOff,
    int* __restrict__ totals)
{
    int node = blockIdx.x * blockDim.x + threadIdx.x;
    if (node >= N_NODES) return;
    int s = 0;
    #pragma unroll
    for (int r = 0; r < NREP; ++r) {
        repOff[r * N_NODES + node] = s;
        s += rcnt[(r * N_NODES + node) * RPAD];
    }
    totals[node] = s;
}

// ---------------------------------------------------------------------------
// K3a/b/c: multi-block exclusive scan of totals -> rowptr
// ---------------------------------------------------------------------------
__global__ __launch_bounds__(256) void blocksum_kernel(
    const int* __restrict__ totals, int* __restrict__ bsums)
{
    __shared__ int red[4];
    int i = blockIdx.x * 256 + threadIdx.x;
    int v = (i < N_NODES) ? totals[i] : 0;
    #pragma unroll
    for (int off = 32; off > 0; off >>= 1) v += __shfl_xor(v, off, 64);
    if ((threadIdx.x & 63) == 0) red[threadIdx.x >> 6] = v;
    __syncthreads();
    if (threadIdx.x == 0) bsums[blockIdx.x] = red[0] + red[1] + red[2] + red[3];
}

__global__ __launch_bounds__(512) void scanbsums_kernel(
    int* __restrict__ bsums, int* __restrict__ rowptr)
{
    __shared__ int s[512];
    int t = threadIdx.x;
    int v = (t < SCAN_BLOCKS) ? bsums[t] : 0;
    s[t] = v;
    __syncthreads();
    for (int off = 1; off < 512; off <<= 1) {
        int o = (t >= off) ? s[t - off] : 0;
        __syncthreads();
        s[t] += o;
        __syncthreads();
    }
    if (t < SCAN_BLOCKS) bsums[t] = s[t] - v;   // exclusive block offset
    if (t == SCAN_BLOCKS - 1) rowptr[N_NODES] = s[t];
}

__global__ __launch_bounds__(256) void blockscan_kernel(
    const int* __restrict__ totals, const int* __restrict__ bsums,
    int* __restrict__ rowptr)
{
    __shared__ int s[256];
    int t = threadIdx.x;
    int i = blockIdx.x * 256 + t;
    int v = (i < N_NODES) ? totals[i] : 0;
    s[t] = v;
    __syncthreads();
    for (int off = 1; off < 256; off <<= 1) {
        int o = (t >= off) ? s[t - off] : 0;
        __syncthreads();
        s[t] += o;
        __syncthreads();
    }
    if (i < N_NODES) rowptr[i] = s[t] - v + bsums[blockIdx.x];
}

// ---------------------------------------------------------------------------
// K4: atomic-free CSR permute:
//     sorted_dst[rowptr[src] + repOff[rep][src] + rank] = dst
// ---------------------------------------------------------------------------
__global__ __launch_bounds__(256) void scatter_kernel(
    const int* __restrict__ ei, const int* __restrict__ rank,
    const int* __restrict__ rowptr, const int* __restrict__ repOff,
    int* __restrict__ sorted_dst)
{
    int e = blockIdx.x * blockDim.x + threadIdx.x;
    if (e >= N_EDGES) return;
    int src = __builtin_nontemporal_load(&ei[e]);
    int dst = __builtin_nontemporal_load(&ei[N_EDGES + e]);
    int pr  = __builtin_nontemporal_load(&rank[e]);
    int rep = pr >> 24;
    int r   = pr & 0xFFFFFF;
    int p = rowptr[src] + repOff[rep * N_NODES + src] + r;
    __builtin_nontemporal_store(dst, &sorted_dst[p]);
}

// ---------------------------------------------------------------------------
// K5: aggregate + fused L2 normalize -> h0 (f16). One wave per node.
// Lane loads uint2 (4 f16); 32 lanes cover a 128-feat row; wave halves
// process 2 edges at once; main loop 8 edges/iter (4 gathers in flight).
// ---------------------------------------------------------------------------
__global__ __launch_bounds__(256) void aggregate_kernel(
    const int* __restrict__ rowptr, const int* __restrict__ sorted_dst,
    const uint2* __restrict__ featsU2,   // [N][32] : 4 f16 each
    _Float16* __restrict__ h0)
{
    int node = (blockIdx.x * blockDim.x + threadIdx.x) >> 6;
    int lane = threadIdx.x & 63;
    if (node >= N_NODES) return;
    const int h = lane >> 5;        // half 0/1
    const int s = lane & 31;        // covers features 4s..4s+3
    const uint2* fb = featsU2 + s;
    int start = rowptr[node], end = rowptr[node + 1];
    float a0 = 0.f, a1 = 0.f, a2 = 0.f, a3 = 0.f;
    union { unsigned int u; _Float16 f[2]; } c;
    int i = start;
    for (; i + 8 <= end; i += 8) {
        int d0 = sorted_dst[i + h];
        int d1 = sorted_dst[i + 2 + h];
        int d2 = sorted_dst[i + 4 + h];
        int d3 = sorted_dst[i + 6 + h];
        uint2 u0 = fb[(long long)d0 * 32];
        uint2 u1 = fb[(long long)d1 * 32];
        uint2 u2 = fb[(long long)d2 * 32];
        uint2 u3 = fb[(long long)d3 * 32];
        c.u = u0.x; a0 += (float)c.f[0]; a1 += (float)c.f[1];
        c.u = u0.y; a2 += (float)c.f[0]; a3 += (float)c.f[1];
        c.u = u1.x; a0 += (float)c.f[0]; a1 += (float)c.f[1];
        c.u = u1.y; a2 += (float)c.f[0]; a3 += (float)c.f[1];
        c.u = u2.x; a0 += (float)c.f[0]; a1 += (float)c.f[1];
        c.u = u2.y; a2 += (float)c.f[0]; a3 += (float)c.f[1];
        c.u = u3.x; a0 += (float)c.f[0]; a1 += (float)c.f[1];
        c.u = u3.y; a2 += (float)c.f[0]; a3 += (float)c.f[1];
    }
    for (; i + 2 <= end; i += 2) {
        int d = sorted_dst[i + h];
        uint2 u = fb[(long long)d * 32];
        c.u = u.x; a0 += (float)c.f[0]; a1 += (float)c.f[1];
        c.u = u.y; a2 += (float)c.f[0]; a3 += (float)c.f[1];
    }
    if (i < end && h == 0) {
        int d = sorted_dst[i];
        uint2 u = fb[(long long)d * 32];
        c.u = u.x; a0 += (float)c.f[0]; a1 += (float)c.f[1];
        c.u = u.y; a2 += (float)c.f[0]; a3 += (float)c.f[1];
    }
    // merge the two halves (both end holding the full sum)
    a0 += __shfl_xor(a0, 32, 64);
    a1 += __shfl_xor(a1, 32, 64);
    a2 += __shfl_xor(a2, 32, 64);
    a3 += __shfl_xor(a3, 32, 64);
    float ss = a0 * a0 + a1 * a1 + a2 * a2 + a3 * a3;
    #pragma unroll
    for (int off = 16; off > 0; off >>= 1) ss += __shfl_xor(ss, off, 64);
    float inv = 1.0f / sqrtf(ss);
    if (h == 0) {
        union { uint2 u; _Float16 f[4]; } o;
        o.f[0] = (_Float16)(a0 * inv); o.f[1] = (_Float16)(a1 * inv);
        o.f[2] = (_Float16)(a2 * inv); o.f[3] = (_Float16)(a3 * inv);
        *reinterpret_cast<uint2*>(&h0[(long long)node * 128 + s * 4]) = o.u;
    }
}

// ---------------------------------------------------------------------------
// K6: MFMA GEMM  C[M,256] = relu(A[M,K] @ WT^T + bias), f16 in/out
// BM=64, BN=256, BK=32; 256 threads = 4 waves (2x2)
// fuseOut: skip C store; dot rows with W4, block-reduce into partials[blk]
// ---------------------------------------------------------------------------
__global__ __launch_bounds__(256) void gemm_f16_kernel(
    const _Float16* __restrict__ A,     // [M][K]
    const _Float16* __restrict__ BT,    // [256][K]
    const float* __restrict__ bias,     // [256]
    _Float16* __restrict__ C,           // [M][256] (unused if fuseOut)
    const float* __restrict__ W4,       // [256]    (used if fuseOut)
    float* __restrict__ partials,       // [gridDim.x] (used if fuseOut)
    int M, int K, int fuseOut)
{
    __shared__ __align__(16) _Float16 sA[64 * 32];      // 4 KB
    __shared__ __align__(16) _Float16 sB[256 * 32];     // 16 KB
    __shared__ float redf[4];

    const int t = threadIdx.x;
    const int row0 = blockIdx.x * 64;

    // staging: linear LDS dest, pre-swizzled global source
    const int ar = t >> 2;
    const int ap = t & 3;
    const int ag = ap ^ ((ar >> 1) & 3);
    int arow = row0 + ar; if (arow > M - 1) arow = M - 1;
    const _Float16* aSrc = A + (long long)arow * K + ag * 8;
    char* aDst = (char*)sA + t * 16;

    const int bc0 = t >> 2;
    const int gb = ap ^ ((bc0 >> 1) & 3);
    const _Float16* bSrc = BT + (long long)bc0 * K + gb * 8;
    char* bDst = (char*)sB + t * 16;

    const int w = t >> 6, lane = t & 63;
    const int wr = w >> 1, wc = w & 1;
    const int lrow = lane & 15, g = lane >> 4;

    unsigned int offA[2], offB[8];
    #pragma unroll
    for (int rt = 0; rt < 2; ++rt) {
        int r = wr * 32 + rt * 16 + lrow;
        offA[rt] = r * 64 + (g ^ ((r >> 1) & 3)) * 16;
    }
    #pragma unroll
    for (int ct = 0; ct < 8; ++ct) {
        int cidx = wc * 128 + ct * 16 + lrow;
        offB[ct] = cidx * 64 + (g ^ ((cidx >> 1) & 3)) * 16;
    }

    f32x4 acc[2][8];
    #pragma unroll
    for (int i = 0; i < 2; ++i)
        #pragma unroll
        for (int j = 0; j < 8; ++j)
            acc[i][j] = (f32x4){0.f, 0.f, 0.f, 0.f};

    for (int k0 = 0; k0 < K; k0 += 32) {
        __syncthreads();
        gload16(aSrc + k0, aDst);
        #pragma unroll
        for (int j = 0; j < 4; ++j)
            gload16(bSrc + (long long)j * 64 * K + k0, bDst + j * 4096);
        __syncthreads();

        half8 a[2], b[8];
        #pragma unroll
        for (int rt = 0; rt < 2; ++rt)
            a[rt] = *reinterpret_cast<const half8*>((const char*)sA + offA[rt]);
        #pragma unroll
        for (int ct = 0; ct < 8; ++ct)
            b[ct] = *reinterpret_cast<const half8*>((const char*)sB + offB[ct]);
        #pragma unroll
        for (int rt = 0; rt < 2; ++rt)
            #pragma unroll
            for (int ct = 0; ct < 8; ++ct)
                acc[rt][ct] = __builtin_amdgcn_mfma_f32_16x16x32_f16(a[rt], b[ct], acc[rt][ct], 0, 0, 0);
    }

    // epilogue.  C/D map: col = lane&15 (lrow), row = g*4 + j
    if (!fuseOut) {
        #pragma unroll
        for (int ct = 0; ct < 8; ++ct) {
            int col = wc * 128 + ct * 16 + lrow;
            float bb = bias[col];
            #pragma unroll
            for (int rt = 0; rt < 2; ++rt) {
                #pragma unroll
                for (int j = 0; j < 4; ++j) {
                    int row = row0 + wr * 32 + rt * 16 + g * 4 + j;
                    if (row < M) {
                        float v = fmaxf(acc[rt][ct][j] + bb, 0.f);
                        C[(long long)row * 256 + col] = (_Float16)v;
                    }
                }
            }
        }
    } else {
        float sum = 0.f;
        #pragma unroll
        for (int ct = 0; ct < 8; ++ct) {
            int col = wc * 128 + ct * 16 + lrow;
            float bb = bias[col];
            float w4 = W4[col];
            #pragma unroll
            for (int rt = 0; rt < 2; ++rt) {
                #pragma unroll
                for (int j = 0; j < 4; ++j) {
                    int row = row0 + wr * 32 + rt * 16 + g * 4 + j;
                    if (row < M) {
                        float v = fmaxf(acc[rt][ct][j] + bb, 0.f);
                        sum += v * w4;
                    }
                }
            }
        }
        #pragma unroll
        for (int off = 32; off > 0; off >>= 1) sum += __shfl_xor(sum, off, 64);
        if (lane == 0) redf[w] = sum;
        __syncthreads();
        if (t == 0) partials[blockIdx.x] = redf[0] + redf[1] + redf[2] + redf[3];
    }
}

// ---------------------------------------------------------------------------
// K7: final mean: out = sum(partials)/N + b4
// ---------------------------------------------------------------------------
__global__ __launch_bounds__(256) void final_kernel(
    const float* __restrict__ partials, int n,
    const float* __restrict__ b4, float* __restrict__ out)
{
    __shared__ float buf[256];
    float s = 0.f;
    for (int i = threadIdx.x; i < n; i += 256) s += partials[i];
    buf[threadIdx.x] = s;
    __syncthreads();
    for (int off = 128; off > 0; off >>= 1) {
        if (threadIdx.x < off) buf[threadIdx.x] += buf[threadIdx.x + off];
        __syncthreads();
    }
    if (threadIdx.x == 0) out[0] = buf[0] / (float)N_NODES + b4[0];
}

// ---------------------------------------------------------------------------
extern "C" void kernel_launch(void* const* d_in, const int* in_sizes, int n_in,
                              void* d_out, int out_size, void* d_ws, size_t ws_size,
                              hipStream_t stream)
{
    const float* x   = (const float*)d_in[0];
    const float* pos = (const float*)d_in[1];
    const float* z   = (const float*)d_in[2];
    const int*   ei  = (const int*)d_in[3];
    const float* W1  = (const float*)d_in[4];
    const float* b1  = (const float*)d_in[5];
    const float* W2  = (const float*)d_in[6];
    const float* b2  = (const float*)d_in[7];
    const float* W3  = (const float*)d_in[8];
    const float* b3  = (const float*)d_in[9];
    const float* W4  = (const float*)d_in[10];
    const float* b4  = (const float*)d_in[11];
    float* out = (float*)d_out;

    char* ws = (char*)d_ws;
    _Float16* feats     = (_Float16*)(ws);                 //  25,600,000
    _Float16* h0        = (_Float16*)(ws +  25600000);     //  25,600,000
    _Float16* h1        = (_Float16*)(ws +  51200000);     //  51,200,000
    _Float16* h2        = (_Float16*)(ws + 102400000);     //  51,200,000
    int*      rcnt      = (int*)     (ws + 153600000);     //  12,800,000
    int*      repOff    = (int*)     (ws + 166400000);     //   3,200,000
    int*      totals    = (int*)     (ws + 169600000);     //     400,000
    int*      rowptr    = (int*)     (ws + 170000000);     //     400,004
    int*      rank      = (int*)     (ws + 170400064);     //  12,800,000
    int*      sortedDst = (int*)     (ws + 183200064);     //  12,800,000
    int*      bsums     = (int*)     (ws + 196000064);     //       6,272
    _Float16* WT1       = (_Float16*)(ws + 196006336);     //      65,536
    _Float16* WT2       = (_Float16*)(ws + 196071872);     //     131,072
    _Float16* WT3       = (_Float16*)(ws + 196202944);     //     131,072
    float*    partials  = (float*)   (ws + 196334016);     //       6,252

    const int gblocks = (N_NODES + 63) / 64;   // 1563

    // weight prep
    wprep_kernel<<<(128 * 256 + 255) / 256, 256, 0, stream>>>(W1, 128, WT1);
    wprep_kernel<<<(256 * 256 + 255) / 256, 256, 0, stream>>>(W2, 256, WT2);
    wprep_kernel<<<(256 * 256 + 255) / 256, 256, 0, stream>>>(W3, 256, WT3);

    // pack features (f16)
    pack_kernel<<<(N_NODES * 128 + 255) / 256, 256, 0, stream>>>(x, pos, z, feats);

    // histogram + rank claim (XCD-local replica counters)
    hipMemsetAsync(rcnt, 0, (size_t)NREP * N_NODES * RPAD * sizeof(int), stream);
    hist_rank_kernel<<<(N_EDGES + 255) / 256, 256, 0, stream>>>(ei, rcnt, rank);

    // replica-offset scan + rowptr scan
    repscan_kernel<<<(N_NODES + 255) / 256, 256, 0, stream>>>(rcnt, repOff, totals);
    blocksum_kernel<<<SCAN_BLOCKS, 256, 0, stream>>>(totals, bsums);
    scanbsums_kernel<<<1, 512, 0, stream>>>(bsums, rowptr);
    blockscan_kernel<<<SCAN_BLOCKS, 256, 0, stream>>>(totals, bsums, rowptr);

    // atomic-free CSR permute
    scatter_kernel<<<(N_EDGES + 255) / 256, 256, 0, stream>>>(
        ei, rank, rowptr, repOff, sortedDst);

    // aggregate + normalize -> h0 (f16)
    aggregate_kernel<<<(N_NODES * 64 + 255) / 256, 256, 0, stream>>>(
        rowptr, sortedDst, (const uint2*)feats, h0);

    // GEMMs (MFMA f16); GEMM3 fused with out-dot
    gemm_f16_kernel<<<gblocks, 256, 0, stream>>>(h0, WT1, b1, h1, nullptr, nullptr, N_NODES, 128, 0);
    gemm_f16_kernel<<<gblocks, 256, 0, stream>>>(h1, WT2, b2, h2, nullptr, nullptr, N_NODES, 256, 0);
    gemm_f16_kernel<<<gblocks, 256, 0, stream>>>(h2, WT3, b3, nullptr, W4, partials, N_NODES, 256, 1);

    // final mean
    final_kernel<<<1, 256, 0, stream>>>(partials, gblocks, b4, out);
}

// Round 7
// 443.324 us; speedup vs baseline: 4.2119x; 1.1859x over previous
//
#include <hip/hip_runtime.h>
#include <math.h>

#define N_NODES 100000
#define N_EDGES 3200000
#define SCAN_BLOCKS ((N_NODES + 255) / 256)   // 391
#define NREP 8                                 // one counter replica per XCD
#define RPAD 4                                 // 16B per counter (4 ints)

typedef _Float16 half8 __attribute__((ext_vector_type(8)));
typedef float f32x4 __attribute__((ext_vector_type(4)));

__device__ __forceinline__ void gload16(const void* gsrc, void* ldst) {
    __builtin_amdgcn_global_load_lds(
        (const __attribute__((address_space(1))) unsigned int*)gsrc,
        (__attribute__((address_space(3))) unsigned int*)ldst,
        16, 0, 0);
}

__device__ __forceinline__ int xcc_id() {
    int x;
    asm("s_getreg_b32 %0, hwreg(HW_REG_XCC_ID)" : "=s"(x));
    return x & (NREP - 1);
}

// ---------------------------------------------------------------------------
// K0: pack feats[N,128] (f16) = concat(x[124], pos[3], z[1])
// ---------------------------------------------------------------------------
__global__ __launch_bounds__(256) void pack_kernel(
    const float* __restrict__ x, const float* __restrict__ pos,
    const float* __restrict__ z, _Float16* __restrict__ feats)
{
    int idx = blockIdx.x * blockDim.x + threadIdx.x;
    if (idx >= N_NODES * 128) return;
    int n = idx >> 7, f = idx & 127;
    float v;
    if (f < 124)      v = x[n * 124 + f];
    else if (f < 127) v = pos[n * 3 + (f - 124)];
    else              v = z[n];
    feats[idx] = (_Float16)v;
}

// ---------------------------------------------------------------------------
// weight prep: W[K,256] f32 -> WT [256,K] f16
// ---------------------------------------------------------------------------
__global__ __launch_bounds__(256) void wprep_kernel(
    const float* __restrict__ W, int K, _Float16* __restrict__ WT)
{
    int idx = blockIdx.x * blockDim.x + threadIdx.x;
    if (idx >= K * 256) return;
    int k = idx >> 8, c = idx & 255;
    WT[c * K + k] = (_Float16)W[idx];
}

// ---------------------------------------------------------------------------
// K1: histogram + rank claim on XCD-local replica counters.
// rank packs replica id in bits 24+.
// ---------------------------------------------------------------------------
__global__ __launch_bounds__(256) void hist_rank_kernel(
    const int* __restrict__ ei, int* __restrict__ rcnt,
    int* __restrict__ rank)
{
    int e = blockIdx.x * blockDim.x + threadIdx.x;
    if (e >= N_EDGES) return;
    int rep = xcc_id();
    int src = __builtin_nontemporal_load(&ei[e]);
    int r = __hip_atomic_fetch_add(&rcnt[(rep * N_NODES + src) * RPAD], 1,
                                   __ATOMIC_RELAXED, __HIP_MEMORY_SCOPE_WORKGROUP);
    __builtin_nontemporal_store(r | (rep << 24), &rank[e]);
}

// ---------------------------------------------------------------------------
// K2: per-node replica-offset scan: repOff[r][n] = sum_{r'<r} cnt[r'][n];
//     totals[n] = sum_r cnt[r][n]
// ---------------------------------------------------------------------------
__global__ __launch_bounds__(256) void repscan_kernel(
    const int* __restrict__ rcnt, int* __restrict__ repOff,
    int* __restrict__ totals)
{
    int node = blockIdx.x * blockDim.x + threadIdx.x;
    if (node >= N_NODES) return;
    int s = 0;
    #pragma unroll
    for (int r = 0; r < NREP; ++r) {
        repOff[r * N_NODES + node] = s;
        s += rcnt[(r * N_NODES + node) * RPAD];
    }
    totals[node] = s;
}

// ---------------------------------------------------------------------------
// K3a/b/c: multi-block exclusive scan of totals -> rowptr
// ---------------------------------------------------------------------------
__global__ __launch_bounds__(256) void blocksum_kernel(
    const int* __restrict__ totals, int* __restrict__ bsums)
{
    __shared__ int red[4];
    int i = blockIdx.x * 256 + threadIdx.x;
    int v = (i < N_NODES) ? totals[i] : 0;
    #pragma unroll
    for (int off = 32; off > 0; off >>= 1) v += __shfl_xor(v, off, 64);
    if ((threadIdx.x & 63) == 0) red[threadIdx.x >> 6] = v;
    __syncthreads();
    if (threadIdx.x == 0) bsums[blockIdx.x] = red[0] + red[1] + red[2] + red[3];
}

__global__ __launch_bounds__(512) void scanbsums_kernel(
    int* __restrict__ bsums, int* __restrict__ rowptr)
{
    __shared__ int s[512];
    int t = threadIdx.x;
    int v = (t < SCAN_BLOCKS) ? bsums[t] : 0;
    s[t] = v;
    __syncthreads();
    for (int off = 1; off < 512; off <<= 1) {
        int o = (t >= off) ? s[t - off] : 0;
        __syncthreads();
        s[t] += o;
        __syncthreads();
    }
    if (t < SCAN_BLOCKS) bsums[t] = s[t] - v;   // exclusive block offset
    if (t == SCAN_BLOCKS - 1) rowptr[N_NODES] = s[t];
}

__global__ __launch_bounds__(256) void blockscan_kernel(
    const int* __restrict__ totals, const int* __restrict__ bsums,
    int* __restrict__ rowptr)
{
    __shared__ int s[256];
    int t = threadIdx.x;
    int i = blockIdx.x * 256 + t;
    int v = (i < N_NODES) ? totals[i] : 0;
    s[t] = v;
    __syncthreads();
    for (int off = 1; off < 256; off <<= 1) {
        int o = (t >= off) ? s[t - off] : 0;
        __syncthreads();
        s[t] += o;
        __syncthreads();
    }
    if (i < N_NODES) rowptr[i] = s[t] - v + bsums[blockIdx.x];
}

// ---------------------------------------------------------------------------
// K4: atomic-free CSR permute:
//     sorted_dst[rowptr[src] + repOff[rep][src] + rank] = dst
// ---------------------------------------------------------------------------
__global__ __launch_bounds__(256) void scatter_kernel(
    const int* __restrict__ ei, const int* __restrict__ rank,
    const int* __restrict__ rowptr, const int* __restrict__ repOff,
    int* __restrict__ sorted_dst)
{
    int e = blockIdx.x * blockDim.x + threadIdx.x;
    if (e >= N_EDGES) return;
    int src = __builtin_nontemporal_load(&ei[e]);
    int dst = __builtin_nontemporal_load(&ei[N_EDGES + e]);
    int pr  = __builtin_nontemporal_load(&rank[e]);
    int rep = pr >> 24;
    int r   = pr & 0xFFFFFF;
    int p = rowptr[src] + repOff[rep * N_NODES + src] + r;
    __builtin_nontemporal_store(dst, &sorted_dst[p]);
}

// ---------------------------------------------------------------------------
// K5: aggregate + fused L2 normalize -> h0 (f16). One wave per node.
// Lane loads uint2 (4 f16); 32 lanes cover a 128-feat row; wave halves
// process 2 edges at once; main loop 8 edges/iter (4 gathers in flight).
// ---------------------------------------------------------------------------
__global__ __launch_bounds__(256) void aggregate_kernel(
    const int* __restrict__ rowptr, const int* __restrict__ sorted_dst,
    const uint2* __restrict__ featsU2,   // [N][32] : 4 f16 each
    _Float16* __restrict__ h0)
{
    int node = (blockIdx.x * blockDim.x + threadIdx.x) >> 6;
    int lane = threadIdx.x & 63;
    if (node >= N_NODES) return;
    const int h = lane >> 5;        // half 0/1
    const int s = lane & 31;        // covers features 4s..4s+3
    const uint2* fb = featsU2 + s;
    int start = rowptr[node], end = rowptr[node + 1];
    float a0 = 0.f, a1 = 0.f, a2 = 0.f, a3 = 0.f;
    union { unsigned int u; _Float16 f[2]; } c;
    int i = start;
    for (; i + 8 <= end; i += 8) {
        int d0 = sorted_dst[i + h];
        int d1 = sorted_dst[i + 2 + h];
        int d2 = sorted_dst[i + 4 + h];
        int d3 = sorted_dst[i + 6 + h];
        uint2 u0 = fb[(long long)d0 * 32];
        uint2 u1 = fb[(long long)d1 * 32];
        uint2 u2 = fb[(long long)d2 * 32];
        uint2 u3 = fb[(long long)d3 * 32];
        c.u = u0.x; a0 += (float)c.f[0]; a1 += (float)c.f[1];
        c.u = u0.y; a2 += (float)c.f[0]; a3 += (float)c.f[1];
        c.u = u1.x; a0 += (float)c.f[0]; a1 += (float)c.f[1];
        c.u = u1.y; a2 += (float)c.f[0]; a3 += (float)c.f[1];
        c.u = u2.x; a0 += (float)c.f[0]; a1 += (float)c.f[1];
        c.u = u2.y; a2 += (float)c.f[0]; a3 += (float)c.f[1];
        c.u = u3.x; a0 += (float)c.f[0]; a1 += (float)c.f[1];
        c.u = u3.y; a2 += (float)c.f[0]; a3 += (float)c.f[1];
    }
    for (; i + 2 <= end; i += 2) {
        int d = sorted_dst[i + h];
        uint2 u = fb[(long long)d * 32];
        c.u = u.x; a0 += (float)c.f[0]; a1 += (float)c.f[1];
        c.u = u.y; a2 += (float)c.f[0]; a3 += (float)c.f[1];
    }
    if (i < end && h == 0) {
        int d = sorted_dst[i];
        uint2 u = fb[(long long)d * 32];
        c.u = u.x; a0 += (float)c.f[0]; a1 += (float)c.f[1];
        c.u = u.y; a2 += (float)c.f[0]; a3 += (float)c.f[1];
    }
    // merge the two halves (both end holding the full sum)
    a0 += __shfl_xor(a0, 32, 64);
    a1 += __shfl_xor(a1, 32, 64);
    a2 += __shfl_xor(a2, 32, 64);
    a3 += __shfl_xor(a3, 32, 64);
    float ss = a0 * a0 + a1 * a1 + a2 * a2 + a3 * a3;
    #pragma unroll
    for (int off = 16; off > 0; off >>= 1) ss += __shfl_xor(ss, off, 64);
    float inv = 1.0f / sqrtf(ss);
    if (h == 0) {
        union { uint2 u; _Float16 f[4]; } o;
        o.f[0] = (_Float16)(a0 * inv); o.f[1] = (_Float16)(a1 * inv);
        o.f[2] = (_Float16)(a2 * inv); o.f[3] = (_Float16)(a3 * inv);
        *reinterpret_cast<uint2*>(&h0[(long long)node * 128 + s * 4]) = o.u;
    }
}

// ---------------------------------------------------------------------------
// K6: FUSED MLP: per block of 64 rows, compute
//   h1 = relu(h0@W1+b1); h2 = relu(h1@W2+b2); h3 = relu(h2@W3+b3);
//   partials[blk] = sum_rows h3 . W4
// Activations stay in LDS (8 chunks of [64][32] f16, swizzled A-layout).
// 256 threads = 4 waves (2x2); BN=256 so the full next-layer K is block-local.
// ---------------------------------------------------------------------------
__global__ __launch_bounds__(256) void fused_mlp_kernel(
    const _Float16* __restrict__ h0,    // [M][128]
    const _Float16* __restrict__ WT1,   // [256][128]
    const float* __restrict__ b1,
    const _Float16* __restrict__ WT2,   // [256][256]
    const float* __restrict__ b2,
    const _Float16* __restrict__ WT3,   // [256][256]
    const float* __restrict__ b3,
    const float* __restrict__ W4,       // [256]
    float* __restrict__ partials, int M)
{
    __shared__ __align__(16) _Float16 sA[8 * 2048];   // 32 KB: 8 chunks 64x32
    __shared__ __align__(16) _Float16 sB[256 * 32];   // 16 KB
    __shared__ float redf[4];

    const int t = threadIdx.x;
    const int row0 = blockIdx.x * 64;

    // --- staging lanes (linear LDS dest, pre-swizzled global source) ---
    const int ar = t >> 2, ap = t & 3;
    const int ag = ap ^ ((ar >> 1) & 3);
    int arow = row0 + ar; if (arow > M - 1) arow = M - 1;
    const _Float16* aSrc = h0 + (long long)arow * 128 + ag * 8;

    const int bc0 = t >> 2;
    const int gb = ap ^ ((bc0 >> 1) & 3);

    // --- wave tiling ---
    const int w = t >> 6, lane = t & 63;
    const int wr = w >> 1, wc = w & 1;
    const int lrow = lane & 15, g = lane >> 4;

    unsigned int offA[2], offB[8];
    #pragma unroll
    for (int rt = 0; rt < 2; ++rt) {
        int r = wr * 32 + rt * 16 + lrow;
        offA[rt] = r * 64 + (g ^ ((r >> 1) & 3)) * 16;
    }
    #pragma unroll
    for (int ct = 0; ct < 8; ++ct) {
        int cidx = wc * 128 + ct * 16 + lrow;
        offB[ct] = cidx * 64 + (g ^ ((cidx >> 1) & 3)) * 16;
    }

    f32x4 acc[2][8];
    #pragma unroll
    for (int i = 0; i < 2; ++i)
        #pragma unroll
        for (int j = 0; j < 8; ++j)
            acc[i][j] = (f32x4){0.f, 0.f, 0.f, 0.f};

    // writes accumulators (bias+relu, f16) into sA chunks in the swizzled
    // A-layout the ds_read side expects: element [chunk][rowl*32 + slot*8 + ke]
#define STORE_ACTS(BIAS)                                                     \
    {                                                                        \
        _Pragma("unroll")                                                    \
        for (int ct = 0; ct < 8; ++ct) {                                     \
            int col = wc * 128 + ct * 16 + lrow;                             \
            float bb = (BIAS)[col];                                          \
            int chk = col >> 5, kk = col & 31;                               \
            int kg = kk >> 3, ke = kk & 7;                                   \
            _Pragma("unroll")                                                \
            for (int rt = 0; rt < 2; ++rt) {                                 \
                _Pragma("unroll")                                            \
                for (int jj = 0; jj < 4; ++jj) {                             \
                    int rowl = wr * 32 + rt * 16 + g * 4 + jj;               \
                    int slot = kg ^ ((rowl >> 1) & 3);                       \
                    sA[chk * 2048 + rowl * 32 + slot * 8 + ke] =             \
                        (_Float16)fmaxf(acc[rt][ct][jj] + bb, 0.f);          \
                    acc[rt][ct][jj] = 0.f;                                   \
                }                                                            \
            }                                                                \
        }                                                                    \
    }

#define MFMA_CHUNK(KC)                                                       \
    {                                                                        \
        half8 a[2], b[8];                                                    \
        _Pragma("unroll")                                                    \
        for (int rt = 0; rt < 2; ++rt)                                       \
            a[rt] = *reinterpret_cast<const half8*>(                         \
                (const char*)sA + (KC) * 4096 + offA[rt]);                   \
        _Pragma("unroll")                                                    \
        for (int ct = 0; ct < 8; ++ct)                                       \
            b[ct] = *reinterpret_cast<const half8*>(                         \
                (const char*)sB + offB[ct]);                                 \
        _Pragma("unroll")                                                    \
        for (int rt = 0; rt < 2; ++rt)                                       \
            _Pragma("unroll")                                                \
            for (int ct = 0; ct < 8; ++ct)                                   \
                acc[rt][ct] = __builtin_amdgcn_mfma_f32_16x16x32_f16(        \
                    a[rt], b[ct], acc[rt][ct], 0, 0, 0);                     \
    }

    // ---- layer 1: A from global h0 (K=128, 4 chunks) ----
    #pragma unroll
    for (int kc = 0; kc < 4; ++kc) {
        __syncthreads();
        gload16(aSrc + kc * 32, (char*)sA + kc * 4096 + t * 16);
        #pragma unroll
        for (int j = 0; j < 4; ++j)
            gload16(WT1 + (long long)(bc0 + j * 64) * 128 + gb * 8 + kc * 32,
                    (char*)sB + j * 4096 + t * 16);
        __syncthreads();
        MFMA_CHUNK(kc);
    }
    __syncthreads();
    STORE_ACTS(b1);

    // ---- layer 2: A = h1 in LDS (K=256, 8 chunks) ----
    #pragma unroll
    for (int kc = 0; kc < 8; ++kc) {
        __syncthreads();
        #pragma unroll
        for (int j = 0; j < 4; ++j)
            gload16(WT2 + (long long)(bc0 + j * 64) * 256 + gb * 8 + kc * 32,
                    (char*)sB + j * 4096 + t * 16);
        __syncthreads();
        MFMA_CHUNK(kc);
    }
    __syncthreads();
    STORE_ACTS(b2);

    // ---- layer 3: A = h2 in LDS (K=256, 8 chunks) ----
    #pragma unroll
    for (int kc = 0; kc < 8; ++kc) {
        __syncthreads();
        #pragma unroll
        for (int j = 0; j < 4; ++j)
            gload16(WT3 + (long long)(bc0 + j * 64) * 256 + gb * 8 + kc * 32,
                    (char*)sB + j * 4096 + t * 16);
        __syncthreads();
        MFMA_CHUNK(kc);
    }

    // ---- epilogue: bias+relu, dot with W4, block reduce ----
    float sum = 0.f;
    #pragma unroll
    for (int ct = 0; ct < 8; ++ct) {
        int col = wc * 128 + ct * 16 + lrow;
        float bb = b3[col];
        float w4 = W4[col];
        #pragma unroll
        for (int rt = 0; rt < 2; ++rt) {
            #pragma unroll
            for (int jj = 0; jj < 4; ++jj) {
                int row = row0 + wr * 32 + rt * 16 + g * 4 + jj;
                if (row < M) {
                    float v = fmaxf(acc[rt][ct][jj] + bb, 0.f);
                    sum += v * w4;
                }
            }
        }
    }
    #pragma unroll
    for (int off = 32; off > 0; off >>= 1) sum += __shfl_xor(sum, off, 64);
    if (lane == 0) redf[w] = sum;
    __syncthreads();
    if (t == 0) partials[blockIdx.x] = redf[0] + redf[1] + redf[2] + redf[3];
#undef STORE_ACTS
#undef MFMA_CHUNK
}

// ---------------------------------------------------------------------------
// K7: final mean: out = sum(partials)/N + b4
// ---------------------------------------------------------------------------
__global__ __launch_bounds__(256) void final_kernel(
    const float* __restrict__ partials, int n,
    const float* __restrict__ b4, float* __restrict__ out)
{
    __shared__ float buf[256];
    float s = 0.f;
    for (int i = threadIdx.x; i < n; i += 256) s += partials[i];
    buf[threadIdx.x] = s;
    __syncthreads();
    for (int off = 128; off > 0; off >>= 1) {
        if (threadIdx.x < off) buf[threadIdx.x] += buf[threadIdx.x + off];
        __syncthreads();
    }
    if (threadIdx.x == 0) out[0] = buf[0] / (float)N_NODES + b4[0];
}

// ---------------------------------------------------------------------------
extern "C" void kernel_launch(void* const* d_in, const int* in_sizes, int n_in,
                              void* d_out, int out_size, void* d_ws, size_t ws_size,
                              hipStream_t stream)
{
    const float* x   = (const float*)d_in[0];
    const float* pos = (const float*)d_in[1];
    const float* z   = (const float*)d_in[2];
    const int*   ei  = (const int*)d_in[3];
    const float* W1  = (const float*)d_in[4];
    const float* b1  = (const float*)d_in[5];
    const float* W2  = (const float*)d_in[6];
    const float* b2  = (const float*)d_in[7];
    const float* W3  = (const float*)d_in[8];
    const float* b3  = (const float*)d_in[9];
    const float* W4  = (const float*)d_in[10];
    const float* b4  = (const float*)d_in[11];
    float* out = (float*)d_out;

    char* ws = (char*)d_ws;
    _Float16* feats     = (_Float16*)(ws);                 //  25,600,000
    _Float16* h0        = (_Float16*)(ws +  25600000);     //  25,600,000
    int*      rcnt      = (int*)     (ws + 153600000);     //  12,800,000
    int*      repOff    = (int*)     (ws + 166400000);     //   3,200,000
    int*      totals    = (int*)     (ws + 169600000);     //     400,000
    int*      rowptr    = (int*)     (ws + 170000000);     //     400,004
    int*      rank      = (int*)     (ws + 170400064);     //  12,800,000
    int*      sortedDst = (int*)     (ws + 183200064);     //  12,800,000
    int*      bsums     = (int*)     (ws + 196000064);     //       6,272
    _Float16* WT1       = (_Float16*)(ws + 196006336);     //      65,536
    _Float16* WT2       = (_Float16*)(ws + 196071872);     //     131,072
    _Float16* WT3       = (_Float16*)(ws + 196202944);     //     131,072
    float*    partials  = (float*)   (ws + 196334016);     //       6,252

    const int gblocks = (N_NODES + 63) / 64;   // 1563

    // weight prep
    wprep_kernel<<<(128 * 256 + 255) / 256, 256, 0, stream>>>(W1, 128, WT1);
    wprep_kernel<<<(256 * 256 + 255) / 256, 256, 0, stream>>>(W2, 256, WT2);
    wprep_kernel<<<(256 * 256 + 255) / 256, 256, 0, stream>>>(W3, 256, WT3);

    // pack features (f16)
    pack_kernel<<<(N_NODES * 128 + 255) / 256, 256, 0, stream>>>(x, pos, z, feats);

    // histogram + rank claim (XCD-local replica counters)
    hipMemsetAsync(rcnt, 0, (size_t)NREP * N_NODES * RPAD * sizeof(int), stream);
    hist_rank_kernel<<<(N_EDGES + 255) / 256, 256, 0, stream>>>(ei, rcnt, rank);

    // replica-offset scan + rowptr scan
    repscan_kernel<<<(N_NODES + 255) / 256, 256, 0, stream>>>(rcnt, repOff, totals);
    blocksum_kernel<<<SCAN_BLOCKS, 256, 0, stream>>>(totals, bsums);
    scanbsums_kernel<<<1, 512, 0, stream>>>(bsums, rowptr);
    blockscan_kernel<<<SCAN_BLOCKS, 256, 0, stream>>>(totals, bsums, rowptr);

    // atomic-free CSR permute
    scatter_kernel<<<(N_EDGES + 255) / 256, 256, 0, stream>>>(
        ei, rank, rowptr, repOff, sortedDst);

    // aggregate + normalize -> h0 (f16)
    aggregate_kernel<<<(N_NODES * 64 + 255) / 256, 256, 0, stream>>>(
        rowptr, sortedDst, (const uint2*)feats, h0);

    // fused MLP (3 layers + W4 dot) -> partials
    fused_mlp_kernel<<<gblocks, 256, 0, stream>>>(
        h0, WT1, b1, WT2, b2, WT3, b3, W4, partials, N_NODES);

    // final mean
    final_kernel<<<1, 256, 0, stream>>>(partials, gblocks, b4, out);
}

// Round 8
// 420.072 us; speedup vs baseline: 4.4451x; 1.0554x over previous
//
#include <hip/hip_runtime.h>
#include <math.h>

#define N_NODES 100000
#define N_EDGES 3200000
#define NBUCK 782            // ceil(100000/128) coarse buckets (src>>7)
#define BSHIFT 7
#define NBLK_E 1024          // edge-pass blocks
#define EPB 3125             // edges per edge-pass block (1024*3125 = 3.2M exactly)
#define CAP 5120             // max edges per bucket (mean 4096, sd 64 -> +16 sd)

typedef _Float16 half8 __attribute__((ext_vector_type(8)));
typedef float f32x4 __attribute__((ext_vector_type(4)));

__device__ __forceinline__ void gload16(const void* gsrc, void* ldst) {
    __builtin_amdgcn_global_load_lds(
        (const __attribute__((address_space(1))) unsigned int*)gsrc,
        (__attribute__((address_space(3))) unsigned int*)ldst,
        16, 0, 0);
}

// ---------------------------------------------------------------------------
// K0: pack feats[N,128] (f16) = concat(x[124], pos[3], z[1])
// ---------------------------------------------------------------------------
__global__ __launch_bounds__(256) void pack_kernel(
    const float* __restrict__ x, const float* __restrict__ pos,
    const float* __restrict__ z, _Float16* __restrict__ feats)
{
    int idx = blockIdx.x * blockDim.x + threadIdx.x;
    if (idx >= N_NODES * 128) return;
    int n = idx >> 7, f = idx & 127;
    float v;
    if (f < 124)      v = x[n * 124 + f];
    else if (f < 127) v = pos[n * 3 + (f - 124)];
    else              v = z[n];
    feats[idx] = (_Float16)v;
}

// ---------------------------------------------------------------------------
// weight prep: W[K,256] f32 -> WT [256,K] f16
// ---------------------------------------------------------------------------
__global__ __launch_bounds__(256) void wprep_kernel(
    const float* __restrict__ W, int K, _Float16* __restrict__ WT)
{
    int idx = blockIdx.x * blockDim.x + threadIdx.x;
    if (idx >= K * 256) return;
    int k = idx >> 8, c = idx & 255;
    WT[c * K + k] = (_Float16)W[idx];
}

// ---------------------------------------------------------------------------
// K1: coarse histogram per edge-block, all atomics in LDS.
// gcnt[blk][bucket] (row-major, coalesced write)
// ---------------------------------------------------------------------------
__global__ __launch_bounds__(256) void coarse_hist_kernel(
    const int* __restrict__ ei, int* __restrict__ gcnt)
{
    __shared__ int bins[NBUCK];
    int t = threadIdx.x, blk = blockIdx.x;
    for (int b = t; b < NBUCK; b += 256) bins[b] = 0;
    __syncthreads();
    int base = blk * EPB;
    #pragma unroll
    for (int k = 0; k < 13; ++k) {
        int i = t + k * 256;
        if (i < EPB) {
            int src = __builtin_nontemporal_load(&ei[base + i]);
            atomicAdd(&bins[src >> BSHIFT], 1);
        }
    }
    __syncthreads();
    for (int b = t; b < NBUCK; b += 256)
        gcnt[blk * NBUCK + b] = bins[b];
}

// ---------------------------------------------------------------------------
// K2a: per-bucket totals (column sums of gcnt)
// ---------------------------------------------------------------------------
__global__ __launch_bounds__(256) void bucket_tot_kernel(
    const int* __restrict__ gcnt, int* __restrict__ btot)
{
    __shared__ int red[4];
    int b = blockIdx.x, t = threadIdx.x;
    int s = 0;
    for (int blk = t; blk < NBLK_E; blk += 256) s += gcnt[blk * NBUCK + b];
    #pragma unroll
    for (int off = 32; off > 0; off >>= 1) s += __shfl_xor(s, off, 64);
    if ((t & 63) == 0) red[t >> 6] = s;
    __syncthreads();
    if (t == 0) btot[b] = red[0] + red[1] + red[2] + red[3];
}

// ---------------------------------------------------------------------------
// K2b: exclusive scan of 782 bucket totals -> bbase[0..782]
// ---------------------------------------------------------------------------
__global__ __launch_bounds__(1024) void scan_buckets_kernel(
    const int* __restrict__ btot, int* __restrict__ bbase)
{
    __shared__ int s[1024];
    int t = threadIdx.x;
    int v = (t < NBUCK) ? btot[t] : 0;
    s[t] = v;
    __syncthreads();
    for (int off = 1; off < 1024; off <<= 1) {
        int o = (t >= off) ? s[t - off] : 0;
        __syncthreads();
        s[t] += o;
        __syncthreads();
    }
    if (t < NBUCK) bbase[t] = s[t] - v;
    if (t == NBUCK - 1) bbase[NBUCK] = s[t];
}

// ---------------------------------------------------------------------------
// K2c: per-bucket column scan over blocks:
//   gbase[blk][b] = bbase[b] + sum_{blk'<blk} gcnt[blk'][b]
// ---------------------------------------------------------------------------
__global__ __launch_bounds__(256) void colscan_kernel(
    const int* __restrict__ gcnt, const int* __restrict__ bbase,
    int* __restrict__ gbase)
{
    __shared__ int s[NBLK_E];
    int b = blockIdx.x, t = threadIdx.x;
    int v[4];
    #pragma unroll
    for (int k = 0; k < 4; ++k) {
        int blk = t + k * 256;
        v[k] = gcnt[blk * NBUCK + b];
        s[blk] = v[k];
    }
    __syncthreads();
    for (int off = 1; off < NBLK_E; off <<= 1) {
        int o[4];
        #pragma unroll
        for (int k = 0; k < 4; ++k) {
            int blk = t + k * 256;
            o[k] = (blk >= off) ? s[blk - off] : 0;
        }
        __syncthreads();
        #pragma unroll
        for (int k = 0; k < 4; ++k) s[t + k * 256] += o[k];
        __syncthreads();
    }
    int bb = bbase[b];
    #pragma unroll
    for (int k = 0; k < 4; ++k) {
        int blk = t + k * 256;
        gbase[blk * NBUCK + b] = bb + s[blk] - v[k];
    }
}

// ---------------------------------------------------------------------------
// K3: bucket scatter (LDS-atomic ranks): bucketed[pos] = dst | (src&127)<<17
// ---------------------------------------------------------------------------
__global__ __launch_bounds__(256) void bucket_scatter_kernel(
    const int* __restrict__ ei, const int* __restrict__ gbase,
    unsigned int* __restrict__ bucketed)
{
    __shared__ int myoff[NBUCK];
    __shared__ int bins[NBUCK];
    int t = threadIdx.x, blk = blockIdx.x;
    for (int b = t; b < NBUCK; b += 256) {
        myoff[b] = gbase[blk * NBUCK + b];
        bins[b] = 0;
    }
    __syncthreads();
    int base = blk * EPB;
    #pragma unroll
    for (int k = 0; k < 13; ++k) {
        int i = t + k * 256;
        if (i < EPB) {
            int e = base + i;
            int src = __builtin_nontemporal_load(&ei[e]);
            int dst = __builtin_nontemporal_load(&ei[N_EDGES + e]);
            int b = src >> BSHIFT;
            int r = atomicAdd(&bins[b], 1);
            unsigned int packed = (unsigned int)dst |
                                  ((unsigned int)(src & 127) << 17);
            __builtin_nontemporal_store(packed, &bucketed[myoff[b] + r]);
        }
    }
}

// ---------------------------------------------------------------------------
// K4: per-bucket LDS counting sort + gather-aggregate + L2 normalize -> h0
// One block per bucket (128 nodes). 4 waves; wave w owns nodes w*32..w*32+31.
// ---------------------------------------------------------------------------
__global__ __launch_bounds__(256) void sortagg_kernel(
    const int* __restrict__ bbase, const unsigned int* __restrict__ bucketed,
    const uint2* __restrict__ featsU2, _Float16* __restrict__ h0)
{
    __shared__ unsigned int raw[CAP];
    __shared__ unsigned int srt[CAP];
    __shared__ int excl[128], cur[128];

    int t = threadIdx.x, b = blockIdx.x;
    int segs = bbase[b], cnt = bbase[b + 1] - segs;

    if (t < 128) cur[t] = 0;
    __syncthreads();

    // phase 1: load + fine histogram
    for (int i = t; i < cnt; i += 256) {
        unsigned int p = bucketed[segs + i];
        raw[i] = p;
        atomicAdd(&cur[(p >> 17) & 127], 1);
    }
    __syncthreads();

    // phase 2: scan 128 bins
    int v = (t < 128) ? cur[t] : 0;
    if (t < 128) excl[t] = v;
    __syncthreads();
    for (int off = 1; off < 128; off <<= 1) {
        int o = (t >= off && t < 128) ? excl[t - off] : 0;
        __syncthreads();
        if (t < 128) excl[t] += o;
        __syncthreads();
    }
    if (t < 128) { excl[t] -= v; cur[t] = excl[t]; }
    __syncthreads();

    // phase 3: counting-sort into srt (dst only)
    for (int i = t; i < cnt; i += 256) {
        unsigned int p = raw[i];
        int r = atomicAdd(&cur[(p >> 17) & 127], 1);
        srt[r] = p & 0x1FFFFu;
    }
    __syncthreads();
    // now: node nl's edges are srt[excl[nl] .. cur[nl])

    // phase 4: aggregate per node
    int w = t >> 6, lane = t & 63;
    int h = lane >> 5, s = lane & 31;
    const uint2* fb = featsU2 + s;
    union { unsigned int u; _Float16 f[2]; } c;

    for (int j = 0; j < 32; ++j) {
        int nl = w * 32 + j;
        int node = b * 128 + nl;
        if (node >= N_NODES) break;
        int start = excl[nl], end = cur[nl];
        float a0 = 0.f, a1 = 0.f, a2 = 0.f, a3 = 0.f;
        int i = start;
        for (; i + 8 <= end; i += 8) {
            int d0 = srt[i + h];
            int d1 = srt[i + 2 + h];
            int d2 = srt[i + 4 + h];
            int d3 = srt[i + 6 + h];
            uint2 u0 = fb[(long long)d0 * 32];
            uint2 u1 = fb[(long long)d1 * 32];
            uint2 u2 = fb[(long long)d2 * 32];
            uint2 u3 = fb[(long long)d3 * 32];
            c.u = u0.x; a0 += (float)c.f[0]; a1 += (float)c.f[1];
            c.u = u0.y; a2 += (float)c.f[0]; a3 += (float)c.f[1];
            c.u = u1.x; a0 += (float)c.f[0]; a1 += (float)c.f[1];
            c.u = u1.y; a2 += (float)c.f[0]; a3 += (float)c.f[1];
            c.u = u2.x; a0 += (float)c.f[0]; a1 += (float)c.f[1];
            c.u = u2.y; a2 += (float)c.f[0]; a3 += (float)c.f[1];
            c.u = u3.x; a0 += (float)c.f[0]; a1 += (float)c.f[1];
            c.u = u3.y; a2 += (float)c.f[0]; a3 += (float)c.f[1];
        }
        for (; i + 2 <= end; i += 2) {
            int d = srt[i + h];
            uint2 u = fb[(long long)d * 32];
            c.u = u.x; a0 += (float)c.f[0]; a1 += (float)c.f[1];
            c.u = u.y; a2 += (float)c.f[0]; a3 += (float)c.f[1];
        }
        if (i < end && h == 0) {
            int d = srt[i];
            uint2 u = fb[(long long)d * 32];
            c.u = u.x; a0 += (float)c.f[0]; a1 += (float)c.f[1];
            c.u = u.y; a2 += (float)c.f[0]; a3 += (float)c.f[1];
        }
        a0 += __shfl_xor(a0, 32, 64);
        a1 += __shfl_xor(a1, 32, 64);
        a2 += __shfl_xor(a2, 32, 64);
        a3 += __shfl_xor(a3, 32, 64);
        float ss = a0 * a0 + a1 * a1 + a2 * a2 + a3 * a3;
        #pragma unroll
        for (int off = 16; off > 0; off >>= 1) ss += __shfl_xor(ss, off, 64);
        float inv = 1.0f / sqrtf(ss);
        if (h == 0) {
            union { uint2 u; _Float16 f[4]; } o;
            o.f[0] = (_Float16)(a0 * inv); o.f[1] = (_Float16)(a1 * inv);
            o.f[2] = (_Float16)(a2 * inv); o.f[3] = (_Float16)(a3 * inv);
            *reinterpret_cast<uint2*>(&h0[(long long)node * 128 + s * 4]) = o.u;
        }
    }
}

// ---------------------------------------------------------------------------
// K5: FUSED MLP (3 layers + W4 dot) per 64-row block; acts live in LDS
// ---------------------------------------------------------------------------
__global__ __launch_bounds__(256) void fused_mlp_kernel(
    const _Float16* __restrict__ h0,    // [M][128]
    const _Float16* __restrict__ WT1,   // [256][128]
    const float* __restrict__ b1,
    const _Float16* __restrict__ WT2,   // [256][256]
    const float* __restrict__ b2,
    const _Float16* __restrict__ WT3,   // [256][256]
    const float* __restrict__ b3,
    const float* __restrict__ W4,       // [256]
    float* __restrict__ partials, int M)
{
    __shared__ __align__(16) _Float16 sA[8 * 2048];   // 32 KB: 8 chunks 64x32
    __shared__ __align__(16) _Float16 sB[256 * 32];   // 16 KB
    __shared__ float redf[4];

    const int t = threadIdx.x;
    const int row0 = blockIdx.x * 64;

    const int ar = t >> 2, ap = t & 3;
    const int ag = ap ^ ((ar >> 1) & 3);
    int arow = row0 + ar; if (arow > M - 1) arow = M - 1;
    const _Float16* aSrc = h0 + (long long)arow * 128 + ag * 8;

    const int bc0 = t >> 2;
    const int gb = ap ^ ((bc0 >> 1) & 3);

    const int w = t >> 6, lane = t & 63;
    const int wr = w >> 1, wc = w & 1;
    const int lrow = lane & 15, g = lane >> 4;

    unsigned int offA[2], offB[8];
    #pragma unroll
    for (int rt = 0; rt < 2; ++rt) {
        int r = wr * 32 + rt * 16 + lrow;
        offA[rt] = r * 64 + (g ^ ((r >> 1) & 3)) * 16;
    }
    #pragma unroll
    for (int ct = 0; ct < 8; ++ct) {
        int cidx = wc * 128 + ct * 16 + lrow;
        offB[ct] = cidx * 64 + (g ^ ((cidx >> 1) & 3)) * 16;
    }

    f32x4 acc[2][8];
    #pragma unroll
    for (int i = 0; i < 2; ++i)
        #pragma unroll
        for (int j = 0; j < 8; ++j)
            acc[i][j] = (f32x4){0.f, 0.f, 0.f, 0.f};

#define STORE_ACTS(BIAS)                                                     \
    {                                                                        \
        _Pragma("unroll")                                                    \
        for (int ct = 0; ct < 8; ++ct) {                                     \
            int col = wc * 128 + ct * 16 + lrow;                             \
            float bb = (BIAS)[col];                                          \
            int chk = col >> 5, kk = col & 31;                               \
            int kg = kk >> 3, ke = kk & 7;                                   \
            _Pragma("unroll")                                                \
            for (int rt = 0; rt < 2; ++rt) {                                 \
                _Pragma("unroll")                                            \
                for (int jj = 0; jj < 4; ++jj) {                             \
                    int rowl = wr * 32 + rt * 16 + g * 4 + jj;               \
                    int slot = kg ^ ((rowl >> 1) & 3);                       \
                    sA[chk * 2048 + rowl * 32 + slot * 8 + ke] =             \
                        (_Float16)fmaxf(acc[rt][ct][jj] + bb, 0.f);          \
                    acc[rt][ct][jj] = 0.f;                                   \
                }                                                            \
            }                                                                \
        }                                                                    \
    }

#define MFMA_CHUNK(KC)                                                       \
    {                                                                        \
        half8 a[2], b[8];                                                    \
        _Pragma("unroll")                                                    \
        for (int rt = 0; rt < 2; ++rt)                                       \
            a[rt] = *reinterpret_cast<const half8*>(                         \
                (const char*)sA + (KC) * 4096 + offA[rt]);                   \
        _Pragma("unroll")                                                    \
        for (int ct = 0; ct < 8; ++ct)                                       \
            b[ct] = *reinterpret_cast<const half8*>(                         \
                (const char*)sB + offB[ct]);                                 \
        _Pragma("unroll")                                                    \
        for (int rt = 0; rt < 2; ++rt)                                       \
            _Pragma("unroll")                                                \
            for (int ct = 0; ct < 8; ++ct)                                   \
                acc[rt][ct] = __builtin_amdgcn_mfma_f32_16x16x32_f16(        \
                    a[rt], b[ct], acc[rt][ct], 0, 0, 0);                     \
    }

    // layer 1: A from global h0 (K=128, 4 chunks)
    #pragma unroll
    for (int kc = 0; kc < 4; ++kc) {
        __syncthreads();
        gload16(aSrc + kc * 32, (char*)sA + kc * 4096 + t * 16);
        #pragma unroll
        for (int j = 0; j < 4; ++j)
            gload16(WT1 + (long long)(bc0 + j * 64) * 128 + gb * 8 + kc * 32,
                    (char*)sB + j * 4096 + t * 16);
        __syncthreads();
        MFMA_CHUNK(kc);
    }
    __syncthreads();
    STORE_ACTS(b1);

    // layer 2
    #pragma unroll
    for (int kc = 0; kc < 8; ++kc) {
        __syncthreads();
        #pragma unroll
        for (int j = 0; j < 4; ++j)
            gload16(WT2 + (long long)(bc0 + j * 64) * 256 + gb * 8 + kc * 32,
                    (char*)sB + j * 4096 + t * 16);
        __syncthreads();
        MFMA_CHUNK(kc);
    }
    __syncthreads();
    STORE_ACTS(b2);

    // layer 3
    #pragma unroll
    for (int kc = 0; kc < 8; ++kc) {
        __syncthreads();
        #pragma unroll
        for (int j = 0; j < 4; ++j)
            gload16(WT3 + (long long)(bc0 + j * 64) * 256 + gb * 8 + kc * 32,
                    (char*)sB + j * 4096 + t * 16);
        __syncthreads();
        MFMA_CHUNK(kc);
    }

    // epilogue: bias+relu, dot W4, block reduce
    float sum = 0.f;
    #pragma unroll
    for (int ct = 0; ct < 8; ++ct) {
        int col = wc * 128 + ct * 16 + lrow;
        float bb = b3[col];
        float w4 = W4[col];
        #pragma unroll
        for (int rt = 0; rt < 2; ++rt) {
            #pragma unroll
            for (int jj = 0; jj < 4; ++jj) {
                int row = row0 + wr * 32 + rt * 16 + g * 4 + jj;
                if (row < M) {
                    float v = fmaxf(acc[rt][ct][jj] + bb, 0.f);
                    sum += v * w4;
                }
            }
        }
    }
    #pragma unroll
    for (int off = 32; off > 0; off >>= 1) sum += __shfl_xor(sum, off, 64);
    if (lane == 0) redf[w] = sum;
    __syncthreads();
    if (t == 0) partials[blockIdx.x] = redf[0] + redf[1] + redf[2] + redf[3];
#undef STORE_ACTS
#undef MFMA_CHUNK
}

// ---------------------------------------------------------------------------
// K6: final mean: out = sum(partials)/N + b4
// ---------------------------------------------------------------------------
__global__ __launch_bounds__(256) void final_kernel(
    const float* __restrict__ partials, int n,
    const float* __restrict__ b4, float* __restrict__ out)
{
    __shared__ float buf[256];
    float s = 0.f;
    for (int i = threadIdx.x; i < n; i += 256) s += partials[i];
    buf[threadIdx.x] = s;
    __syncthreads();
    for (int off = 128; off > 0; off >>= 1) {
        if (threadIdx.x < off) buf[threadIdx.x] += buf[threadIdx.x + off];
        __syncthreads();
    }
    if (threadIdx.x == 0) out[0] = buf[0] / (float)N_NODES + b4[0];
}

// ---------------------------------------------------------------------------
extern "C" void kernel_launch(void* const* d_in, const int* in_sizes, int n_in,
                              void* d_out, int out_size, void* d_ws, size_t ws_size,
                              hipStream_t stream)
{
    const float* x   = (const float*)d_in[0];
    const float* pos = (const float*)d_in[1];
    const float* z   = (const float*)d_in[2];
    const int*   ei  = (const int*)d_in[3];
    const float* W1  = (const float*)d_in[4];
    const float* b1  = (const float*)d_in[5];
    const float* W2  = (const float*)d_in[6];
    const float* b2  = (const float*)d_in[7];
    const float* W3  = (const float*)d_in[8];
    const float* b3  = (const float*)d_in[9];
    const float* W4  = (const float*)d_in[10];
    const float* b4  = (const float*)d_in[11];
    float* out = (float*)d_out;

    char* ws = (char*)d_ws;
    _Float16*     feats    = (_Float16*)    (ws);              //  25,600,000
    _Float16*     h0       = (_Float16*)    (ws + 25600000);   //  25,600,000
    int*          gcnt     = (int*)         (ws + 51200000);   //   3,203,072
    int*          gbase    = (int*)         (ws + 54403072);   //   3,203,072
    int*          btot     = (int*)         (ws + 57606144);   //       3,128
    int*          bbase    = (int*)         (ws + 57609280);   //       3,132
    unsigned int* bucketed = (unsigned int*)(ws + 57612416);   //  12,800,000
    _Float16*     WT1      = (_Float16*)    (ws + 70412416);   //      65,536
    _Float16*     WT2      = (_Float16*)    (ws + 70477952);   //     131,072
    _Float16*     WT3      = (_Float16*)    (ws + 70609024);   //     131,072
    float*        partials = (float*)       (ws + 70740096);   //       6,252

    const int gblocks = (N_NODES + 63) / 64;   // 1563

    // weight prep
    wprep_kernel<<<(128 * 256 + 255) / 256, 256, 0, stream>>>(W1, 128, WT1);
    wprep_kernel<<<(256 * 256 + 255) / 256, 256, 0, stream>>>(W2, 256, WT2);
    wprep_kernel<<<(256 * 256 + 255) / 256, 256, 0, stream>>>(W3, 256, WT3);

    // pack features (f16)
    pack_kernel<<<(N_NODES * 128 + 255) / 256, 256, 0, stream>>>(x, pos, z, feats);

    // CSR build via two-level bucket sort (LDS atomics only)
    coarse_hist_kernel<<<NBLK_E, 256, 0, stream>>>(ei, gcnt);
    bucket_tot_kernel<<<NBUCK, 256, 0, stream>>>(gcnt, btot);
    scan_buckets_kernel<<<1, 1024, 0, stream>>>(btot, bbase);
    colscan_kernel<<<NBUCK, 256, 0, stream>>>(gcnt, bbase, gbase);
    bucket_scatter_kernel<<<NBLK_E, 256, 0, stream>>>(ei, gbase, bucketed);

    // per-bucket sort + aggregate + normalize -> h0 (f16)
    sortagg_kernel<<<NBUCK, 256, 0, stream>>>(bbase, bucketed, (const uint2*)feats, h0);

    // fused MLP (3 layers + W4 dot) -> partials
    fused_mlp_kernel<<<gblocks, 256, 0, stream>>>(
        h0, WT1, b1, WT2, b2, WT3, b3, W4, partials, N_NODES);

    // final mean
    final_kernel<<<1, 256, 0, stream>>>(partials, gblocks, b4, out);
}